// Round 8
// baseline (828.694 us; speedup 1.0000x reference)
//
#include <hip/hip_runtime.h>
#include <hip/hip_bf16.h>
#include <math.h>

#define NNODES 50000
#define NEDGES 500000

__device__ __forceinline__ float lrelu(float x) { return x > 0.f ? x : 0.2f * x; }

__device__ __forceinline__ unsigned short f2bf(float f) {
    unsigned int u = __float_as_uint(f);
    u += 0x7FFFu + ((u >> 16) & 1u);   // round-nearest-even
    return (unsigned short)(u >> 16);
}

// ============ per-type fused kernel: embed GEMM -> h ; h@WgO, h@WgS ; att scores ============
// 64 rows x 128 cols per block, 256 threads: j4 = t&31 (col quad), r = t>>5, rows r+8p (p=0..7).
// h staged in LDS as bf16 pairs packed along k -> GEMM2: 1 LDS dword = 2 k-steps per row.
template <int K>
__launch_bounds__(256)
__global__ void xp_all_kernel(const float* __restrict__ X,
                              const float* __restrict__ Wt, const float* __restrict__ bt,
                              const float* __restrict__ WgO, const float* __restrict__ asO,
                              const float* __restrict__ adO,
                              const float* __restrict__ WgS, const float* __restrict__ asS,
                              const float* __restrict__ adS,
                              float* __restrict__ emb,
                              unsigned short* __restrict__ xpO, unsigned short* __restrict__ xpS,
                              float* __restrict__ ssO, float* __restrict__ sdO,
                              float* __restrict__ ssS, float* __restrict__ sdS, int n) {
    __shared__ float xs[64][K];
    __shared__ unsigned hs[64][64];   // h as 2xbf16 packed along col: hs[row][c2] = {col 2*c2, 2*c2+1}
    const int t = threadIdx.x;
    const int j4 = t & 31, r = t >> 5;
    const int row0 = blockIdx.x * 64;

    constexpr int KQ = K / 4;
    for (int f = t; f < 64 * KQ; f += 256) {
        int row = f / KQ, kq = f - row * KQ;
        float4 v = {0.f, 0.f, 0.f, 0.f};
        if (row0 + row < n) v = *(const float4*)&X[(size_t)(row0 + row) * K + kq * 4];
        *(float4*)&xs[row][kq * 4] = v;
    }
    __syncthreads();

    // GEMM1: h = X @ Wt + bt  (f32; 8 rows/thread)
    float4 h[8];
#pragma unroll
    for (int p = 0; p < 8; p++) h[p] = {0.f, 0.f, 0.f, 0.f};
#pragma unroll 4
    for (int k = 0; k < K; k++) {
        float4 w = *(const float4*)&Wt[k * 128 + j4 * 4];
#pragma unroll
        for (int p = 0; p < 8; p++) {
            float x = xs[r + 8 * p][k];
            h[p].x += x * w.x; h[p].y += x * w.y; h[p].z += x * w.z; h[p].w += x * w.w;
        }
    }
    float4 bv = *(const float4*)&bt[j4 * 4];
#pragma unroll
    for (int p = 0; p < 8; p++) {
        h[p].x += bv.x; h[p].y += bv.y; h[p].z += bv.z; h[p].w += bv.w;
        int row = row0 + r + 8 * p;
        if (row < n) *(float4*)&emb[(size_t)row * 128 + j4 * 4] = h[p];
        // pack to bf16 pairs: cols j4*4..j4*4+3 -> hs[row][j4*2], hs[row][j4*2+1]
        unsigned u0 = (unsigned)f2bf(h[p].x) | ((unsigned)f2bf(h[p].y) << 16);
        unsigned u1 = (unsigned)f2bf(h[p].z) | ((unsigned)f2bf(h[p].w) << 16);
        hs[r + 8 * p][j4 * 2] = u0;
        hs[r + 8 * p][j4 * 2 + 1] = u1;
    }
    __syncthreads();

    // GEMM2: xpO = h @ WgO, xpS = h @ WgS  (bf16 h from LDS, 2 k per dword)
    float4 aO[8], aS[8];
#pragma unroll
    for (int p = 0; p < 8; p++) { aO[p] = {0.f, 0.f, 0.f, 0.f}; aS[p] = {0.f, 0.f, 0.f, 0.f}; }
#pragma unroll 2
    for (int kk = 0; kk < 64; kk++) {
        float4 wo0 = *(const float4*)&WgO[(2 * kk) * 128 + j4 * 4];
        float4 wo1 = *(const float4*)&WgO[(2 * kk + 1) * 128 + j4 * 4];
        float4 ws0 = *(const float4*)&WgS[(2 * kk) * 128 + j4 * 4];
        float4 ws1 = *(const float4*)&WgS[(2 * kk + 1) * 128 + j4 * 4];
#pragma unroll
        for (int p = 0; p < 8; p++) {
            unsigned u = hs[r + 8 * p][kk];
            float x0 = __uint_as_float(u << 16);            // even k
            float x1 = __uint_as_float(u & 0xFFFF0000u);    // odd k
            aO[p].x += x0 * wo0.x + x1 * wo1.x;
            aO[p].y += x0 * wo0.y + x1 * wo1.y;
            aO[p].z += x0 * wo0.z + x1 * wo1.z;
            aO[p].w += x0 * wo0.w + x1 * wo1.w;
            aS[p].x += x0 * ws0.x + x1 * ws1.x;
            aS[p].y += x0 * ws0.y + x1 * ws1.y;
            aS[p].z += x0 * ws0.z + x1 * ws1.z;
            aS[p].w += x0 * ws0.w + x1 * ws1.w;
        }
    }

    float4 vasO = *(const float4*)&asO[j4 * 4];
    float4 vadO = *(const float4*)&adO[j4 * 4];
    float4 vasS = *(const float4*)&asS[j4 * 4];
    float4 vadS = *(const float4*)&adS[j4 * 4];
#pragma unroll
    for (int p = 0; p < 8; p++) {
        int row = row0 + r + 8 * p;
        if (row < n) {
            ushort4 uo, us;
            uo.x = f2bf(aO[p].x); uo.y = f2bf(aO[p].y); uo.z = f2bf(aO[p].z); uo.w = f2bf(aO[p].w);
            us.x = f2bf(aS[p].x); us.y = f2bf(aS[p].y); us.z = f2bf(aS[p].z); us.w = f2bf(aS[p].w);
            *(ushort4*)&xpO[(size_t)row * 128 + j4 * 4] = uo;
            *(ushort4*)&xpS[(size_t)row * 128 + j4 * 4] = us;
        }
        float psO = aO[p].x * vasO.x + aO[p].y * vasO.y + aO[p].z * vasO.z + aO[p].w * vasO.w;
        float pdO = aO[p].x * vadO.x + aO[p].y * vadO.y + aO[p].z * vadO.z + aO[p].w * vadO.w;
        float psS = aS[p].x * vasS.x + aS[p].y * vasS.y + aS[p].z * vasS.z + aS[p].w * vasS.w;
        float pdS = aS[p].x * vadS.x + aS[p].y * vadS.y + aS[p].z * vadS.z + aS[p].w * vadS.w;
#pragma unroll
        for (int o = 4; o > 0; o >>= 1) {
            psO += __shfl_xor(psO, o);
            pdO += __shfl_xor(pdO, o);
            psS += __shfl_xor(psS, o);
            pdS += __shfl_xor(pdS, o);
        }
        if ((j4 & 7) == 0 && row < n) {
            int hidx = row * 4 + (j4 >> 3);
            ssO[hidx] = psO; sdO[hidx] = pdO;
            ssS[hidx] = psS; sdS[hidx] = pdS;
        }
    }
}

// ============ CSR build (R2-proven single-block scan) ============
__global__ void zero_int(int* __restrict__ p, int n) {
    int i = blockIdx.x * blockDim.x + threadIdx.x;
    if (i < n) p[i] = 0;
}

__global__ void count_kernel(const int* __restrict__ dst, int e, int* __restrict__ counts) {
    int i = blockIdx.x * blockDim.x + threadIdx.x;
    if (i < e) atomicAdd(&counts[dst[i]], 1);
}

__global__ void scan_kernel(const int* __restrict__ counts, int* __restrict__ row_ptr,
                            int* __restrict__ cursor, int n) {
    __shared__ int wsum[16];
    __shared__ int s_carry;
    const int tid = threadIdx.x;           // 1024
    const int lane = tid & 63, wid = tid >> 6;
    if (tid == 0) s_carry = 0;
    __syncthreads();
    for (int base = 0; base < n; base += 1024) {
        int i = base + tid;
        int v = (i < n) ? counts[i] : 0;
        int x = v;
#pragma unroll
        for (int o = 1; o < 64; o <<= 1) {
            int tt = __shfl_up(x, o);
            if (lane >= o) x += tt;
        }
        if (lane == 63) wsum[wid] = x;
        __syncthreads();
        if (wid == 0) {
            int ws = (lane < 16) ? wsum[lane] : 0;
#pragma unroll
            for (int o = 1; o < 16; o <<= 1) {
                int tt = __shfl_up(ws, o);
                if (lane >= o) ws += tt;
            }
            if (lane < 16) wsum[lane] = ws;   // inclusive wave-sum scan
        }
        __syncthreads();
        int wave_excl = (wid == 0) ? 0 : wsum[wid - 1];
        int carry = s_carry;
        int excl = carry + wave_excl + x - v;
        if (i < n) { row_ptr[i] = excl; cursor[i] = excl; }
        __syncthreads();
        if (tid == 1023) s_carry = carry + wsum[15];
    }
    __syncthreads();
    if (tid == 0) row_ptr[n] = s_carry;
}

// scatter with packed (edge_id, src) per slot
__global__ void scatter_pack_kernel(const int* __restrict__ src, const int* __restrict__ dst, int e,
                                    int* __restrict__ cursor, long long* __restrict__ colp) {
    int i = blockIdx.x * blockDim.x + threadIdx.x;
    if (i < e) {
        int d = dst[i];
        int p = atomicAdd(&cursor[d], 1);
        colp[p] = ((long long)i << 32) | (unsigned)src[i];
    }
}

// ============ pass A: per-edge raw attention weights (all 4 heads), no atomics ============
__global__ void alpha_kernel(const int* __restrict__ ei, const float* __restrict__ ss,
                             const float* __restrict__ sd, float* __restrict__ al, int e) {
    int i = blockIdx.x * blockDim.x + threadIdx.x;
    if (i >= e) return;
    int s = ei[i], d = ei[e + i];
    float4 svs = *(const float4*)&ss[s * 4];
    float4 svd = *(const float4*)&ss[d * 4];
    float4 dvd = *(const float4*)&sd[d * 4];
    float4 a;
    a.x = __expf(lrelu(svs.x + dvd.x) - lrelu(svd.x + dvd.x));
    a.y = __expf(lrelu(svs.y + dvd.y) - lrelu(svd.y + dvd.y));
    a.z = __expf(lrelu(svs.z + dvd.z) - lrelu(svd.z + dvd.z));
    a.w = __expf(lrelu(svs.w + dvd.w) - lrelu(svd.w + dvd.w));
    *(float4*)&al[(size_t)i * 4] = a;
}

// ============ pass B: wave per dst node; gather with precomputed alphas; denom from same loop ============
__device__ __forceinline__ void aggB(const unsigned short* __restrict__ xp,
                                     const float* __restrict__ al,
                                     const long long* __restrict__ colp,
                                     const int* __restrict__ rp,
                                     int i, int c, int hh, float& ax, float& ay) {
    const int r0 = rp[i], r1 = rp[i + 1];
    float t = 0.f, ox = 0.f, oy = 0.f;
    int k = r0;
    for (; k + 2 <= r1; k += 2) {
        long long v0 = colp[k], v1 = colp[k + 1];
        int s0 = (int)(v0 & 0xFFFFFFFFll), e0 = (int)(v0 >> 32);
        int s1 = (int)(v1 & 0xFFFFFFFFll), e1 = (int)(v1 >> 32);
        float a0 = al[(size_t)e0 * 4 + hh];
        float a1 = al[(size_t)e1 * 4 + hh];
        unsigned u0 = *(const unsigned*)&xp[(size_t)s0 * 128 + c];
        unsigned u1 = *(const unsigned*)&xp[(size_t)s1 * 128 + c];
        t += a0 + a1;
        ox += a0 * __uint_as_float(u0 << 16) + a1 * __uint_as_float(u1 << 16);
        oy += a0 * __uint_as_float(u0 & 0xFFFF0000u) + a1 * __uint_as_float(u1 & 0xFFFF0000u);
    }
    if (k < r1) {
        long long v0 = colp[k];
        int s0 = (int)(v0 & 0xFFFFFFFFll), e0 = (int)(v0 >> 32);
        float a0 = al[(size_t)e0 * 4 + hh];
        unsigned u0 = *(const unsigned*)&xp[(size_t)s0 * 128 + c];
        t += a0;
        ox += a0 * __uint_as_float(u0 << 16);
        oy += a0 * __uint_as_float(u0 & 0xFFFF0000u);
    }
    {   // self-loop: raw alpha = exp(0) = 1
        unsigned u = *(const unsigned*)&xp[(size_t)i * 128 + c];
        ox += __uint_as_float(u << 16);
        oy += __uint_as_float(u & 0xFFFF0000u);
    }
    const float id = 1.f / (t + 1.f);
    ax += id * ox;
    ay += id * oy;
}

__global__ void gat_fused_kernel(const unsigned short* __restrict__ xpO, const float* __restrict__ alO,
                                 const long long* __restrict__ cpO, const int* __restrict__ rpO,
                                 const float* __restrict__ bgO,
                                 const unsigned short* __restrict__ xpS, const float* __restrict__ alS,
                                 const long long* __restrict__ cpS, const int* __restrict__ rpS,
                                 const float* __restrict__ bgS,
                                 const float* __restrict__ emb, const float* __restrict__ Wc,
                                 const float* __restrict__ bc, float* __restrict__ out, int n) {
    const int wave = threadIdx.x >> 6, lane = threadIdx.x & 63;
    const int i = blockIdx.x * 4 + wave;
    if (i >= n) return;
    const int c = lane * 2, hh = lane >> 4;

    float ax = 0.f, ay = 0.f;
    aggB(xpO, alO, cpO, rpO, i, c, hh, ax, ay);
    aggB(xpS, alS, cpS, rpS, i, c, hh, ax, ay);

    float2 e = *(const float2*)&emb[(size_t)i * 128 + c];
    float fx = e.x + ax + bgO[c] + bgS[c];
    float fy = e.y + ay + bgO[c + 1] + bgS[c + 1];

    float2 w = *(const float2*)&Wc[c];
    float p = fx * w.x + fy * w.y;
#pragma unroll
    for (int o = 32; o > 0; o >>= 1) p += __shfl_xor(p, o);
    if (lane == 0) out[i] = 1.f / (1.f + expf(-(p + bc[0])));
}

extern "C" void kernel_launch(void* const* d_in, const int* in_sizes, int n_in,
                              void* d_out, int out_size, void* d_ws, size_t ws_size,
                              hipStream_t stream) {
    const int N = NNODES, E = NEDGES;
    const float* x_acc = (const float*)d_in[0];
    const float* x_cus = (const float*)d_in[1];
    const float* x_txn = (const float*)d_in[2];
    const int* ei_owns = (const int*)d_in[4];
    const int* ei_shr = (const int*)d_in[5];
    const float* W_acc = (const float*)d_in[6];
    const float* b_acc = (const float*)d_in[7];
    const float* W_cus = (const float*)d_in[8];
    const float* b_cus = (const float*)d_in[9];
    const float* W_txn = (const float*)d_in[10];
    const float* b_txn = (const float*)d_in[11];
    const float* Wg_o = (const float*)d_in[12];
    const float* as_o = (const float*)d_in[13];
    const float* ad_o = (const float*)d_in[14];
    const float* bg_o = (const float*)d_in[15];
    const float* Wg_s = (const float*)d_in[16];
    const float* as_s = (const float*)d_in[17];
    const float* ad_s = (const float*)d_in[18];
    const float* bg_s = (const float*)d_in[19];
    const float* W_cls = (const float*)d_in[20];
    const float* b_cls = (const float*)d_in[21];
    float* out = (float*)d_out;

    float* wf = (float*)d_ws;
    int* iw = (int*)d_ws;
    float* emb = wf;                                                // [0, 6.4M) floats
    unsigned short* xp_o = (unsigned short*)(wf + 6400000);         // 6.4M bf16
    unsigned short* xp_s = (unsigned short*)(wf + 9600000);         // 6.4M bf16
    float* ss_o = wf + 12800000;                                    // 200k
    float* sd_o = wf + 13000000;
    float* ss_s = wf + 13200000;
    float* sd_s = wf + 13400000;
    float* al_o = wf + 13600000;                                    // E*4 = 2M
    float* al_s = wf + 15600000;                                    // 2M
    int* rp_o   = iw + 17600000;                                    // N+1
    int* rp_s   = iw + 17650008;
    long long* cp_o = (long long*)(iw + 17700016);                  // E u64 (byte ofs %8==0)
    long long* cp_s = (long long*)(iw + 18700016);                  // E u64
    int* counts = iw + 19700016;                                    // N
    int* cursor = iw + 19750016;                                    // N

    const int gE = (E + 255) / 256, gN = (N + 255) / 256;
    const int gT = (N + 63) / 64;       // xp_all tiles (64 rows/block)
    const int gA = (N + 3) / 4;         // aggregate (wave per node)

    // CSR for the two live edge types (src = row 0, dst = row 1)
    zero_int<<<gN, 256, 0, stream>>>(counts, N);
    count_kernel<<<gE, 256, 0, stream>>>(ei_owns + E, E, counts);
    scan_kernel<<<1, 1024, 0, stream>>>(counts, rp_o, cursor, N);
    scatter_pack_kernel<<<gE, 256, 0, stream>>>(ei_owns, ei_owns + E, E, cursor, cp_o);
    zero_int<<<gN, 256, 0, stream>>>(counts, N);
    count_kernel<<<gE, 256, 0, stream>>>(ei_shr + E, E, counts);
    scan_kernel<<<1, 1024, 0, stream>>>(counts, rp_s, cursor, N);
    scatter_pack_kernel<<<gE, 256, 0, stream>>>(ei_shr, ei_shr + E, E, cursor, cp_s);

    // per type: fused embed+xp+scores -> edge alphas -> fused aggregate+residual+classifier
    xp_all_kernel<64><<<gT, 256, 0, stream>>>(x_acc, W_acc, b_acc, Wg_o, as_o, ad_o,
                                              Wg_s, as_s, ad_s, emb, xp_o, xp_s,
                                              ss_o, sd_o, ss_s, sd_s, N);
    alpha_kernel<<<gE, 256, 0, stream>>>(ei_owns, ss_o, sd_o, al_o, E);
    alpha_kernel<<<gE, 256, 0, stream>>>(ei_shr, ss_s, sd_s, al_s, E);
    gat_fused_kernel<<<gA, 256, 0, stream>>>(xp_o, al_o, cp_o, rp_o, bg_o,
                                             xp_s, al_s, cp_s, rp_s, bg_s,
                                             emb, W_cls, b_cls, out, N);

    xp_all_kernel<32><<<gT, 256, 0, stream>>>(x_cus, W_cus, b_cus, Wg_o, as_o, ad_o,
                                              Wg_s, as_s, ad_s, emb, xp_o, xp_s,
                                              ss_o, sd_o, ss_s, sd_s, N);
    alpha_kernel<<<gE, 256, 0, stream>>>(ei_owns, ss_o, sd_o, al_o, E);
    alpha_kernel<<<gE, 256, 0, stream>>>(ei_shr, ss_s, sd_s, al_s, E);
    gat_fused_kernel<<<gA, 256, 0, stream>>>(xp_o, al_o, cp_o, rp_o, bg_o,
                                             xp_s, al_s, cp_s, rp_s, bg_s,
                                             emb, W_cls, b_cls, out + N, N);

    xp_all_kernel<128><<<gT, 256, 0, stream>>>(x_txn, W_txn, b_txn, Wg_o, as_o, ad_o,
                                               Wg_s, as_s, ad_s, emb, xp_o, xp_s,
                                               ss_o, sd_o, ss_s, sd_s, N);
    alpha_kernel<<<gE, 256, 0, stream>>>(ei_owns, ss_o, sd_o, al_o, E);
    alpha_kernel<<<gE, 256, 0, stream>>>(ei_shr, ss_s, sd_s, al_s, E);
    gat_fused_kernel<<<gA, 256, 0, stream>>>(xp_o, al_o, cp_o, rp_o, bg_o,
                                             xp_s, al_s, cp_s, rp_s, bg_s,
                                             emb, W_cls, b_cls, out + 2 * N, N);
}

// Round 10
// 814.994 us; speedup vs baseline: 1.0168x; 1.0168x over previous
//
#include <hip/hip_runtime.h>
#include <hip/hip_bf16.h>
#include <math.h>

#define NNODES 50000
#define NEDGES 500000

__device__ __forceinline__ float lrelu(float x) { return x > 0.f ? x : 0.2f * x; }

__device__ __forceinline__ unsigned short f2bf(float f) {
    unsigned int u = __float_as_uint(f);
    u += 0x7FFFu + ((u >> 16) & 1u);   // round-nearest-even
    return (unsigned short)(u >> 16);
}

// ============ per-type fused kernel: embed GEMM -> h ; h@WgO, h@WgS ; att scores ============
// R7 tile (32 rows x 128 cols, 256 threads, 4 rows/thread) + W staged in LDS (32-k chunks,
// reg-prefetch pipeline) so GEMM inner loops never touch global memory.
template <int K>
__launch_bounds__(256)
__global__ void xp_all_kernel(const float* __restrict__ X,
                              const float* __restrict__ Wt, const float* __restrict__ bt,
                              const float* __restrict__ WgO, const float* __restrict__ asO,
                              const float* __restrict__ adO,
                              const float* __restrict__ WgS, const float* __restrict__ asS,
                              const float* __restrict__ adS,
                              float* __restrict__ emb,
                              unsigned short* __restrict__ xpO, unsigned short* __restrict__ xpS,
                              float* __restrict__ ssO, float* __restrict__ sdO,
                              float* __restrict__ ssS, float* __restrict__ sdS, int n) {
    __shared__ float xs[32][K];
    __shared__ float hs[32][128];
    __shared__ float wb[32][128];       // one 32-k chunk of a weight matrix (16 KB)
    const int t = threadIdx.x;
    const int j4 = t & 31, r = t >> 5;
    const int row0 = blockIdx.x * 32;

    // prefetch first W chunk (Wt rows 0..31) into regs
    float4 wreg[4];
#pragma unroll
    for (int i = 0; i < 4; i++) wreg[i] = ((const float4*)Wt)[t + i * 256];

    constexpr int KQ = K / 4;
    for (int f = t; f < 32 * KQ; f += 256) {
        int row = f / KQ, kq = f - row * KQ;
        float4 v = {0.f, 0.f, 0.f, 0.f};
        if (row0 + row < n) v = *(const float4*)&X[(size_t)(row0 + row) * K + kq * 4];
        *(float4*)&xs[row][kq * 4] = v;
    }
    __syncthreads();

    // ---- GEMM1: h = X @ Wt + bt (f32), W chunks via LDS ----
    float4 h[4];
#pragma unroll
    for (int p = 0; p < 4; p++) h[p] = {0.f, 0.f, 0.f, 0.f};
    for (int kc = 0; kc < K; kc += 32) {
        // wb free here (first iter: xs barrier; later: trailing barrier below)
#pragma unroll
        for (int i = 0; i < 4; i++) ((float4*)wb)[t + i * 256] = wreg[i];
        const float* nxt = (kc + 32 < K) ? (Wt + (size_t)(kc + 32) * 128) : WgO;
#pragma unroll
        for (int i = 0; i < 4; i++) wreg[i] = ((const float4*)nxt)[t + i * 256];
        __syncthreads();
#pragma unroll 4
        for (int kk = 0; kk < 32; kk++) {
            float4 w = *(const float4*)&wb[kk][j4 * 4];
            float x0 = xs[r][kc + kk], x1 = xs[r + 8][kc + kk];
            float x2 = xs[r + 16][kc + kk], x3 = xs[r + 24][kc + kk];
            h[0].x += x0 * w.x; h[0].y += x0 * w.y; h[0].z += x0 * w.z; h[0].w += x0 * w.w;
            h[1].x += x1 * w.x; h[1].y += x1 * w.y; h[1].z += x1 * w.z; h[1].w += x1 * w.w;
            h[2].x += x2 * w.x; h[2].y += x2 * w.y; h[2].z += x2 * w.z; h[2].w += x2 * w.w;
            h[3].x += x3 * w.x; h[3].y += x3 * w.y; h[3].z += x3 * w.z; h[3].w += x3 * w.w;
        }
        __syncthreads();
    }
    float4 bv = *(const float4*)&bt[j4 * 4];
#pragma unroll
    for (int p = 0; p < 4; p++) {
        h[p].x += bv.x; h[p].y += bv.y; h[p].z += bv.z; h[p].w += bv.w;
        int row = row0 + r + 8 * p;
        *(float4*)&hs[r + 8 * p][j4 * 4] = h[p];
        if (row < n) *(float4*)&emb[(size_t)row * 128 + j4 * 4] = h[p];
    }
    // no barrier yet: GEMM2 iter-0 ds_write to wb is safe (trailing GEMM1 barrier),
    // and the barrier inside the first GEMM2 chunk covers the hs writes.

    // ---- GEMM2: xpO = h @ WgO ----
    float4 aO[4], aS[4];
#pragma unroll
    for (int p = 0; p < 4; p++) { aO[p] = {0.f, 0.f, 0.f, 0.f}; aS[p] = {0.f, 0.f, 0.f, 0.f}; }
    for (int kc = 0; kc < 128; kc += 32) {
#pragma unroll
        for (int i = 0; i < 4; i++) ((float4*)wb)[t + i * 256] = wreg[i];
        const float* nxt = (kc + 32 < 128) ? (WgO + (size_t)(kc + 32) * 128) : WgS;
#pragma unroll
        for (int i = 0; i < 4; i++) wreg[i] = ((const float4*)nxt)[t + i * 256];
        __syncthreads();
#pragma unroll 4
        for (int kk = 0; kk < 32; kk++) {
            float4 w = *(const float4*)&wb[kk][j4 * 4];
            float x0 = hs[r][kc + kk], x1 = hs[r + 8][kc + kk];
            float x2 = hs[r + 16][kc + kk], x3 = hs[r + 24][kc + kk];
            aO[0].x += x0 * w.x; aO[0].y += x0 * w.y; aO[0].z += x0 * w.z; aO[0].w += x0 * w.w;
            aO[1].x += x1 * w.x; aO[1].y += x1 * w.y; aO[1].z += x1 * w.z; aO[1].w += x1 * w.w;
            aO[2].x += x2 * w.x; aO[2].y += x2 * w.y; aO[2].z += x2 * w.z; aO[2].w += x2 * w.w;
            aO[3].x += x3 * w.x; aO[3].y += x3 * w.y; aO[3].z += x3 * w.z; aO[3].w += x3 * w.w;
        }
        __syncthreads();
    }
    // ---- GEMM2: xpS = h @ WgS ----
    for (int kc = 0; kc < 128; kc += 32) {
#pragma unroll
        for (int i = 0; i < 4; i++) ((float4*)wb)[t + i * 256] = wreg[i];
        if (kc + 32 < 128) {
            const float* nxt = WgS + (size_t)(kc + 32) * 128;
#pragma unroll
            for (int i = 0; i < 4; i++) wreg[i] = ((const float4*)nxt)[t + i * 256];
        }
        __syncthreads();
#pragma unroll 4
        for (int kk = 0; kk < 32; kk++) {
            float4 w = *(const float4*)&wb[kk][j4 * 4];
            float x0 = hs[r][kc + kk], x1 = hs[r + 8][kc + kk];
            float x2 = hs[r + 16][kc + kk], x3 = hs[r + 24][kc + kk];
            aS[0].x += x0 * w.x; aS[0].y += x0 * w.y; aS[0].z += x0 * w.z; aS[0].w += x0 * w.w;
            aS[1].x += x1 * w.x; aS[1].y += x1 * w.y; aS[1].z += x1 * w.z; aS[1].w += x1 * w.w;
            aS[2].x += x2 * w.x; aS[2].y += x2 * w.y; aS[2].z += x2 * w.z; aS[2].w += x2 * w.w;
            aS[3].x += x3 * w.x; aS[3].y += x3 * w.y; aS[3].z += x3 * w.z; aS[3].w += x3 * w.w;
        }
        __syncthreads();
    }

    float4 vasO = *(const float4*)&asO[j4 * 4];
    float4 vadO = *(const float4*)&adO[j4 * 4];
    float4 vasS = *(const float4*)&asS[j4 * 4];
    float4 vadS = *(const float4*)&adS[j4 * 4];
#pragma unroll
    for (int p = 0; p < 4; p++) {
        int row = row0 + r + 8 * p;
        if (row < n) {
            ushort4 uo, us;
            uo.x = f2bf(aO[p].x); uo.y = f2bf(aO[p].y); uo.z = f2bf(aO[p].z); uo.w = f2bf(aO[p].w);
            us.x = f2bf(aS[p].x); us.y = f2bf(aS[p].y); us.z = f2bf(aS[p].z); us.w = f2bf(aS[p].w);
            *(ushort4*)&xpO[(size_t)row * 128 + j4 * 4] = uo;
            *(ushort4*)&xpS[(size_t)row * 128 + j4 * 4] = us;
        }
        float psO = aO[p].x * vasO.x + aO[p].y * vasO.y + aO[p].z * vasO.z + aO[p].w * vasO.w;
        float pdO = aO[p].x * vadO.x + aO[p].y * vadO.y + aO[p].z * vadO.z + aO[p].w * vadO.w;
        float psS = aS[p].x * vasS.x + aS[p].y * vasS.y + aS[p].z * vasS.z + aS[p].w * vasS.w;
        float pdS = aS[p].x * vadS.x + aS[p].y * vadS.y + aS[p].z * vadS.z + aS[p].w * vadS.w;
#pragma unroll
        for (int o = 4; o > 0; o >>= 1) {
            psO += __shfl_xor(psO, o);
            pdO += __shfl_xor(pdO, o);
            psS += __shfl_xor(psS, o);
            pdS += __shfl_xor(pdS, o);
        }
        if ((j4 & 7) == 0 && row < n) {
            int hidx = row * 4 + (j4 >> 3);
            ssO[hidx] = psO; sdO[hidx] = pdO;
            ssS[hidx] = psS; sdS[hidx] = pdS;
        }
    }
}

// ============ CSR build (R2-proven single-block scan) ============
__global__ void zero_int(int* __restrict__ p, int n) {
    int i = blockIdx.x * blockDim.x + threadIdx.x;
    if (i < n) p[i] = 0;
}

__global__ void count_kernel(const int* __restrict__ dst, int e, int* __restrict__ counts) {
    int i = blockIdx.x * blockDim.x + threadIdx.x;
    if (i < e) atomicAdd(&counts[dst[i]], 1);
}

__global__ void scan_kernel(const int* __restrict__ counts, int* __restrict__ row_ptr,
                            int* __restrict__ cursor, int n) {
    __shared__ int wsum[16];
    __shared__ int s_carry;
    const int tid = threadIdx.x;           // 1024
    const int lane = tid & 63, wid = tid >> 6;
    if (tid == 0) s_carry = 0;
    __syncthreads();
    for (int base = 0; base < n; base += 1024) {
        int i = base + tid;
        int v = (i < n) ? counts[i] : 0;
        int x = v;
#pragma unroll
        for (int o = 1; o < 64; o <<= 1) {
            int tt = __shfl_up(x, o);
            if (lane >= o) x += tt;
        }
        if (lane == 63) wsum[wid] = x;
        __syncthreads();
        if (wid == 0) {
            int ws = (lane < 16) ? wsum[lane] : 0;
#pragma unroll
            for (int o = 1; o < 16; o <<= 1) {
                int tt = __shfl_up(ws, o);
                if (lane >= o) ws += tt;
            }
            if (lane < 16) wsum[lane] = ws;   // inclusive wave-sum scan
        }
        __syncthreads();
        int wave_excl = (wid == 0) ? 0 : wsum[wid - 1];
        int carry = s_carry;
        int excl = carry + wave_excl + x - v;
        if (i < n) { row_ptr[i] = excl; cursor[i] = excl; }
        __syncthreads();
        if (tid == 1023) s_carry = carry + wsum[15];
    }
    __syncthreads();
    if (tid == 0) row_ptr[n] = s_carry;
}

// scatter with packed (edge_id, src) per slot
__global__ void scatter_pack_kernel(const int* __restrict__ src, const int* __restrict__ dst, int e,
                                    int* __restrict__ cursor, long long* __restrict__ colp) {
    int i = blockIdx.x * blockDim.x + threadIdx.x;
    if (i < e) {
        int d = dst[i];
        int p = atomicAdd(&cursor[d], 1);
        colp[p] = ((long long)i << 32) | (unsigned)src[i];
    }
}

// ============ pass A: per-edge raw attention weights (all 4 heads), no atomics ============
__global__ void alpha_kernel(const int* __restrict__ ei, const float* __restrict__ ss,
                             const float* __restrict__ sd, float* __restrict__ al, int e) {
    int i = blockIdx.x * blockDim.x + threadIdx.x;
    if (i >= e) return;
    int s = ei[i], d = ei[e + i];
    float4 svs = *(const float4*)&ss[s * 4];
    float4 svd = *(const float4*)&ss[d * 4];
    float4 dvd = *(const float4*)&sd[d * 4];
    float4 a;
    a.x = __expf(lrelu(svs.x + dvd.x) - lrelu(svd.x + dvd.x));
    a.y = __expf(lrelu(svs.y + dvd.y) - lrelu(svd.y + dvd.y));
    a.z = __expf(lrelu(svs.z + dvd.z) - lrelu(svd.z + dvd.z));
    a.w = __expf(lrelu(svs.w + dvd.w) - lrelu(svd.w + dvd.w));
    *(float4*)&al[(size_t)i * 4] = a;
}

// ============ pass B: wave per dst node; gather with precomputed alphas; denom from same loop ============
__device__ __forceinline__ void aggB(const unsigned short* __restrict__ xp,
                                     const float* __restrict__ al,
                                     const long long* __restrict__ colp,
                                     const int* __restrict__ rp,
                                     int i, int c, int hh, float& ax, float& ay) {
    const int r0 = rp[i], r1 = rp[i + 1];
    float t = 0.f, ox = 0.f, oy = 0.f;
    int k = r0;
    for (; k + 2 <= r1; k += 2) {
        long long v0 = colp[k], v1 = colp[k + 1];
        int s0 = (int)(v0 & 0xFFFFFFFFll), e0 = (int)(v0 >> 32);
        int s1 = (int)(v1 & 0xFFFFFFFFll), e1 = (int)(v1 >> 32);
        float a0 = al[(size_t)e0 * 4 + hh];
        float a1 = al[(size_t)e1 * 4 + hh];
        unsigned u0 = *(const unsigned*)&xp[(size_t)s0 * 128 + c];
        unsigned u1 = *(const unsigned*)&xp[(size_t)s1 * 128 + c];
        t += a0 + a1;
        ox += a0 * __uint_as_float(u0 << 16) + a1 * __uint_as_float(u1 << 16);
        oy += a0 * __uint_as_float(u0 & 0xFFFF0000u) + a1 * __uint_as_float(u1 & 0xFFFF0000u);
    }
    if (k < r1) {
        long long v0 = colp[k];
        int s0 = (int)(v0 & 0xFFFFFFFFll), e0 = (int)(v0 >> 32);
        float a0 = al[(size_t)e0 * 4 + hh];
        unsigned u0 = *(const unsigned*)&xp[(size_t)s0 * 128 + c];
        t += a0;
        ox += a0 * __uint_as_float(u0 << 16);
        oy += a0 * __uint_as_float(u0 & 0xFFFF0000u);
    }
    {   // self-loop: raw alpha = exp(0) = 1
        unsigned u = *(const unsigned*)&xp[(size_t)i * 128 + c];
        ox += __uint_as_float(u << 16);
        oy += __uint_as_float(u & 0xFFFF0000u);
    }
    const float id = 1.f / (t + 1.f);
    ax += id * ox;
    ay += id * oy;
}

__global__ void gat_fused_kernel(const unsigned short* __restrict__ xpO, const float* __restrict__ alO,
                                 const long long* __restrict__ cpO, const int* __restrict__ rpO,
                                 const float* __restrict__ bgO,
                                 const unsigned short* __restrict__ xpS, const float* __restrict__ alS,
                                 const long long* __restrict__ cpS, const int* __restrict__ rpS,
                                 const float* __restrict__ bgS,
                                 const float* __restrict__ emb, const float* __restrict__ Wc,
                                 const float* __restrict__ bc, float* __restrict__ out, int n) {
    const int wave = threadIdx.x >> 6, lane = threadIdx.x & 63;
    const int i = blockIdx.x * 4 + wave;
    if (i >= n) return;
    const int c = lane * 2, hh = lane >> 4;

    float ax = 0.f, ay = 0.f;
    aggB(xpO, alO, cpO, rpO, i, c, hh, ax, ay);
    aggB(xpS, alS, cpS, rpS, i, c, hh, ax, ay);

    float2 e = *(const float2*)&emb[(size_t)i * 128 + c];
    float fx = e.x + ax + bgO[c] + bgS[c];
    float fy = e.y + ay + bgO[c + 1] + bgS[c + 1];

    float2 w = *(const float2*)&Wc[c];
    float p = fx * w.x + fy * w.y;
#pragma unroll
    for (int o = 32; o > 0; o >>= 1) p += __shfl_xor(p, o);
    if (lane == 0) out[i] = 1.f / (1.f + expf(-(p + bc[0])));
}

extern "C" void kernel_launch(void* const* d_in, const int* in_sizes, int n_in,
                              void* d_out, int out_size, void* d_ws, size_t ws_size,
                              hipStream_t stream) {
    const int N = NNODES, E = NEDGES;
    const float* x_acc = (const float*)d_in[0];
    const float* x_cus = (const float*)d_in[1];
    const float* x_txn = (const float*)d_in[2];
    const int* ei_owns = (const int*)d_in[4];
    const int* ei_shr = (const int*)d_in[5];
    const float* W_acc = (const float*)d_in[6];
    const float* b_acc = (const float*)d_in[7];
    const float* W_cus = (const float*)d_in[8];
    const float* b_cus = (const float*)d_in[9];
    const float* W_txn = (const float*)d_in[10];
    const float* b_txn = (const float*)d_in[11];
    const float* Wg_o = (const float*)d_in[12];
    const float* as_o = (const float*)d_in[13];
    const float* ad_o = (const float*)d_in[14];
    const float* bg_o = (const float*)d_in[15];
    const float* Wg_s = (const float*)d_in[16];
    const float* as_s = (const float*)d_in[17];
    const float* ad_s = (const float*)d_in[18];
    const float* bg_s = (const float*)d_in[19];
    const float* W_cls = (const float*)d_in[20];
    const float* b_cls = (const float*)d_in[21];
    float* out = (float*)d_out;

    float* wf = (float*)d_ws;
    int* iw = (int*)d_ws;
    float* emb = wf;                                                // [0, 6.4M) floats
    unsigned short* xp_o = (unsigned short*)(wf + 6400000);         // 6.4M bf16
    unsigned short* xp_s = (unsigned short*)(wf + 9600000);         // 6.4M bf16
    float* ss_o = wf + 12800000;                                    // 200k
    float* sd_o = wf + 13000000;
    float* ss_s = wf + 13200000;
    float* sd_s = wf + 13400000;
    float* al_o = wf + 13600000;                                    // E*4 = 2M
    float* al_s = wf + 15600000;                                    // 2M
    int* rp_o   = iw + 17600000;                                    // N+1
    int* rp_s   = iw + 17650008;
    long long* cp_o = (long long*)(iw + 17700016);                  // E u64 (byte ofs %8==0)
    long long* cp_s = (long long*)(iw + 18700016);                  // E u64
    int* counts = iw + 19700016;                                    // N
    int* cursor = iw + 19750016;                                    // N

    const int gE = (E + 255) / 256, gN = (N + 255) / 256;
    const int gT = (N + 31) / 32;       // xp_all tiles (32 rows/block)
    const int gA = (N + 3) / 4;         // aggregate (wave per node)

    // CSR for the two live edge types (src = row 0, dst = row 1)
    zero_int<<<gN, 256, 0, stream>>>(counts, N);
    count_kernel<<<gE, 256, 0, stream>>>(ei_owns + E, E, counts);
    scan_kernel<<<1, 1024, 0, stream>>>(counts, rp_o, cursor, N);
    scatter_pack_kernel<<<gE, 256, 0, stream>>>(ei_owns, ei_owns + E, E, cursor, cp_o);
    zero_int<<<gN, 256, 0, stream>>>(counts, N);
    count_kernel<<<gE, 256, 0, stream>>>(ei_shr + E, E, counts);
    scan_kernel<<<1, 1024, 0, stream>>>(counts, rp_s, cursor, N);
    scatter_pack_kernel<<<gE, 256, 0, stream>>>(ei_shr, ei_shr + E, E, cursor, cp_s);

    // per type: fused embed+xp+scores -> edge alphas -> fused aggregate+residual+classifier
    xp_all_kernel<64><<<gT, 256, 0, stream>>>(x_acc, W_acc, b_acc, Wg_o, as_o, ad_o,
                                              Wg_s, as_s, ad_s, emb, xp_o, xp_s,
                                              ss_o, sd_o, ss_s, sd_s, N);
    alpha_kernel<<<gE, 256, 0, stream>>>(ei_owns, ss_o, sd_o, al_o, E);
    alpha_kernel<<<gE, 256, 0, stream>>>(ei_shr, ss_s, sd_s, al_s, E);
    gat_fused_kernel<<<gA, 256, 0, stream>>>(xp_o, al_o, cp_o, rp_o, bg_o,
                                             xp_s, al_s, cp_s, rp_s, bg_s,
                                             emb, W_cls, b_cls, out, N);

    xp_all_kernel<32><<<gT, 256, 0, stream>>>(x_cus, W_cus, b_cus, Wg_o, as_o, ad_o,
                                              Wg_s, as_s, ad_s, emb, xp_o, xp_s,
                                              ss_o, sd_o, ss_s, sd_s, N);
    alpha_kernel<<<gE, 256, 0, stream>>>(ei_owns, ss_o, sd_o, al_o, E);
    alpha_kernel<<<gE, 256, 0, stream>>>(ei_shr, ss_s, sd_s, al_s, E);
    gat_fused_kernel<<<gA, 256, 0, stream>>>(xp_o, al_o, cp_o, rp_o, bg_o,
                                             xp_s, al_s, cp_s, rp_s, bg_s,
                                             emb, W_cls, b_cls, out + N, N);

    xp_all_kernel<128><<<gT, 256, 0, stream>>>(x_txn, W_txn, b_txn, Wg_o, as_o, ad_o,
                                               Wg_s, as_s, ad_s, emb, xp_o, xp_s,
                                               ss_o, sd_o, ss_s, sd_s, N);
    alpha_kernel<<<gE, 256, 0, stream>>>(ei_owns, ss_o, sd_o, al_o, E);
    alpha_kernel<<<gE, 256, 0, stream>>>(ei_shr, ss_s, sd_s, al_s, E);
    gat_fused_kernel<<<gA, 256, 0, stream>>>(xp_o, al_o, cp_o, rp_o, bg_o,
                                             xp_s, al_s, cp_s, rp_s, bg_s,
                                             emb, W_cls, b_cls, out + 2 * N, N);
}

// Round 14
// 781.334 us; speedup vs baseline: 1.0606x; 1.0431x over previous
//
#include <hip/hip_runtime.h>
#include <hip/hip_bf16.h>
#include <math.h>

#define NNODES 50000
#define NEDGES 500000

__device__ __forceinline__ float lrelu(float x) { return x > 0.f ? x : 0.2f * x; }

__device__ __forceinline__ unsigned short f2bf(float f) {
    unsigned int u = __float_as_uint(f);
    u += 0x7FFFu + ((u >> 16) & 1u);   // round-nearest-even
    return (unsigned short)(u >> 16);
}

// ============ per-type fused kernel: embed GEMM -> h ; h@WgO, h@WgS ; att scores ============
// R7-proven form: 32 rows x 128 cols, 256 threads, 4 rows/thread, direct global W loads.
template <int K>
__launch_bounds__(256)
__global__ void xp_all_kernel(const float* __restrict__ X,
                              const float* __restrict__ Wt, const float* __restrict__ bt,
                              const float* __restrict__ WgO, const float* __restrict__ asO,
                              const float* __restrict__ adO,
                              const float* __restrict__ WgS, const float* __restrict__ asS,
                              const float* __restrict__ adS,
                              float* __restrict__ emb,
                              unsigned short* __restrict__ xpO, unsigned short* __restrict__ xpS,
                              float* __restrict__ ssO, float* __restrict__ sdO,
                              float* __restrict__ ssS, float* __restrict__ sdS, int n) {
    __shared__ float xs[32][K];
    __shared__ float hs[32][128];
    const int t = threadIdx.x;
    const int j4 = t & 31, r = t >> 5;
    const int row0 = blockIdx.x * 32;

    constexpr int KQ = K / 4;
    for (int f = t; f < 32 * KQ; f += 256) {
        int row = f / KQ, kq = f - row * KQ;
        float4 v = {0.f, 0.f, 0.f, 0.f};
        if (row0 + row < n) v = *(const float4*)&X[(size_t)(row0 + row) * K + kq * 4];
        *(float4*)&xs[row][kq * 4] = v;
    }
    __syncthreads();

    // GEMM1: h = X @ Wt + bt
    float4 h[4];
#pragma unroll
    for (int p = 0; p < 4; p++) h[p] = {0.f, 0.f, 0.f, 0.f};
#pragma unroll 4
    for (int k = 0; k < K; k++) {
        float4 w = *(const float4*)&Wt[k * 128 + j4 * 4];
        float x0 = xs[r][k], x1 = xs[r + 8][k], x2 = xs[r + 16][k], x3 = xs[r + 24][k];
        h[0].x += x0 * w.x; h[0].y += x0 * w.y; h[0].z += x0 * w.z; h[0].w += x0 * w.w;
        h[1].x += x1 * w.x; h[1].y += x1 * w.y; h[1].z += x1 * w.z; h[1].w += x1 * w.w;
        h[2].x += x2 * w.x; h[2].y += x2 * w.y; h[2].z += x2 * w.z; h[2].w += x2 * w.w;
        h[3].x += x3 * w.x; h[3].y += x3 * w.y; h[3].z += x3 * w.z; h[3].w += x3 * w.w;
    }
    float4 bv = *(const float4*)&bt[j4 * 4];
#pragma unroll
    for (int p = 0; p < 4; p++) {
        h[p].x += bv.x; h[p].y += bv.y; h[p].z += bv.z; h[p].w += bv.w;
        int row = row0 + r + 8 * p;
        *(float4*)&hs[r + 8 * p][j4 * 4] = h[p];
        if (row < n) *(float4*)&emb[(size_t)row * 128 + j4 * 4] = h[p];
    }
    __syncthreads();

    // GEMM2: xpO = h @ WgO, xpS = h @ WgS
    float4 aO[4], aS[4];
#pragma unroll
    for (int p = 0; p < 4; p++) { aO[p] = {0.f, 0.f, 0.f, 0.f}; aS[p] = {0.f, 0.f, 0.f, 0.f}; }
#pragma unroll 2
    for (int k = 0; k < 128; k++) {
        float4 wo = *(const float4*)&WgO[k * 128 + j4 * 4];
        float4 ws = *(const float4*)&WgS[k * 128 + j4 * 4];
        float x0 = hs[r][k], x1 = hs[r + 8][k], x2 = hs[r + 16][k], x3 = hs[r + 24][k];
        aO[0].x += x0 * wo.x; aO[0].y += x0 * wo.y; aO[0].z += x0 * wo.z; aO[0].w += x0 * wo.w;
        aO[1].x += x1 * wo.x; aO[1].y += x1 * wo.y; aO[1].z += x1 * wo.z; aO[1].w += x1 * wo.w;
        aO[2].x += x2 * wo.x; aO[2].y += x2 * wo.y; aO[2].z += x2 * wo.z; aO[2].w += x2 * wo.w;
        aO[3].x += x3 * wo.x; aO[3].y += x3 * wo.y; aO[3].z += x3 * wo.z; aO[3].w += x3 * wo.w;
        aS[0].x += x0 * ws.x; aS[0].y += x0 * ws.y; aS[0].z += x0 * ws.z; aS[0].w += x0 * ws.w;
        aS[1].x += x1 * ws.x; aS[1].y += x1 * ws.y; aS[1].z += x1 * ws.z; aS[1].w += x1 * ws.w;
        aS[2].x += x2 * ws.x; aS[2].y += x2 * ws.y; aS[2].z += x2 * ws.z; aS[2].w += x2 * ws.w;
        aS[3].x += x3 * ws.x; aS[3].y += x3 * ws.y; aS[3].z += x3 * ws.z; aS[3].w += x3 * ws.w;
    }

    float4 vasO = *(const float4*)&asO[j4 * 4];
    float4 vadO = *(const float4*)&adO[j4 * 4];
    float4 vasS = *(const float4*)&asS[j4 * 4];
    float4 vadS = *(const float4*)&adS[j4 * 4];
#pragma unroll
    for (int p = 0; p < 4; p++) {
        int row = row0 + r + 8 * p;
        if (row < n) {
            ushort4 uo, us;
            uo.x = f2bf(aO[p].x); uo.y = f2bf(aO[p].y); uo.z = f2bf(aO[p].z); uo.w = f2bf(aO[p].w);
            us.x = f2bf(aS[p].x); us.y = f2bf(aS[p].y); us.z = f2bf(aS[p].z); us.w = f2bf(aS[p].w);
            *(ushort4*)&xpO[(size_t)row * 128 + j4 * 4] = uo;
            *(ushort4*)&xpS[(size_t)row * 128 + j4 * 4] = us;
        }
        float psO = aO[p].x * vasO.x + aO[p].y * vasO.y + aO[p].z * vasO.z + aO[p].w * vasO.w;
        float pdO = aO[p].x * vadO.x + aO[p].y * vadO.y + aO[p].z * vadO.z + aO[p].w * vadO.w;
        float psS = aS[p].x * vasS.x + aS[p].y * vasS.y + aS[p].z * vasS.z + aS[p].w * vasS.w;
        float pdS = aS[p].x * vadS.x + aS[p].y * vadS.y + aS[p].z * vadS.z + aS[p].w * vadS.w;
#pragma unroll
        for (int o = 4; o > 0; o >>= 1) {
            psO += __shfl_xor(psO, o);
            pdO += __shfl_xor(pdO, o);
            psS += __shfl_xor(psS, o);
            pdS += __shfl_xor(pdS, o);
        }
        if ((j4 & 7) == 0 && row < n) {
            int hidx = row * 4 + (j4 >> 3);
            ssO[hidx] = psO; sdO[hidx] = pdO;
            ssS[hidx] = psS; sdS[hidx] = pdS;
        }
    }
}

// ============ CSR build (R2-proven single-block scan) ============
__global__ void zero_int(int* __restrict__ p, int n) {
    int i = blockIdx.x * blockDim.x + threadIdx.x;
    if (i < n) p[i] = 0;
}

__global__ void count_kernel(const int* __restrict__ dst, int e, int* __restrict__ counts) {
    int i = blockIdx.x * blockDim.x + threadIdx.x;
    if (i < e) atomicAdd(&counts[dst[i]], 1);
}

__global__ void scan_kernel(const int* __restrict__ counts, int* __restrict__ row_ptr,
                            int* __restrict__ cursor, int n) {
    __shared__ int wsum[16];
    __shared__ int s_carry;
    const int tid = threadIdx.x;           // 1024
    const int lane = tid & 63, wid = tid >> 6;
    if (tid == 0) s_carry = 0;
    __syncthreads();
    for (int base = 0; base < n; base += 1024) {
        int i = base + tid;
        int v = (i < n) ? counts[i] : 0;
        int x = v;
#pragma unroll
        for (int o = 1; o < 64; o <<= 1) {
            int tt = __shfl_up(x, o);
            if (lane >= o) x += tt;
        }
        if (lane == 63) wsum[wid] = x;
        __syncthreads();
        if (wid == 0) {
            int ws = (lane < 16) ? wsum[lane] : 0;
#pragma unroll
            for (int o = 1; o < 16; o <<= 1) {
                int tt = __shfl_up(ws, o);
                if (lane >= o) ws += tt;
            }
            if (lane < 16) wsum[lane] = ws;   // inclusive wave-sum scan
        }
        __syncthreads();
        int wave_excl = (wid == 0) ? 0 : wsum[wid - 1];
        int carry = s_carry;
        int excl = carry + wave_excl + x - v;
        if (i < n) { row_ptr[i] = excl; cursor[i] = excl; }
        __syncthreads();
        if (tid == 1023) s_carry = carry + wsum[15];
    }
    __syncthreads();
    if (tid == 0) row_ptr[n] = s_carry;
}

// scatter with packed (edge_id, src) per slot
__global__ void scatter_pack_kernel(const int* __restrict__ src, const int* __restrict__ dst, int e,
                                    int* __restrict__ cursor, long long* __restrict__ colp) {
    int i = blockIdx.x * blockDim.x + threadIdx.x;
    if (i < e) {
        int d = dst[i];
        int p = atomicAdd(&cursor[d], 1);
        colp[p] = ((long long)i << 32) | (unsigned)src[i];
    }
}

// canonicalize slot order per row (insertion sort by packed eid) -> deterministic CSR
__global__ void sort_rows_kernel(const int* __restrict__ rp, long long* __restrict__ cp, int n) {
    int i = blockIdx.x * blockDim.x + threadIdx.x;
    if (i >= n) return;
    int r0 = rp[i], r1 = rp[i + 1];
    for (int a = r0 + 1; a < r1; a++) {
        long long v = cp[a];
        int b = a - 1;
        while (b >= r0 && cp[b] > v) {
            cp[b + 1] = cp[b];
            b--;
        }
        cp[b + 1] = v;
    }
}

// ============ pass A: per-edge raw attention weights (all 4 heads), no atomics ============
__global__ void alpha_kernel(const int* __restrict__ ei, const float* __restrict__ ss,
                             const float* __restrict__ sd, float* __restrict__ al, int e) {
    int i = blockIdx.x * blockDim.x + threadIdx.x;
    if (i >= e) return;
    int s = ei[i], d = ei[e + i];
    float4 svs = *(const float4*)&ss[s * 4];
    float4 svd = *(const float4*)&ss[d * 4];
    float4 dvd = *(const float4*)&sd[d * 4];
    float4 a;
    a.x = __expf(lrelu(svs.x + dvd.x) - lrelu(svd.x + dvd.x));
    a.y = __expf(lrelu(svs.y + dvd.y) - lrelu(svd.y + dvd.y));
    a.z = __expf(lrelu(svs.z + dvd.z) - lrelu(svd.z + dvd.z));
    a.w = __expf(lrelu(svs.w + dvd.w) - lrelu(svd.w + dvd.w));
    *(float4*)&al[(size_t)i * 4] = a;
}

// ============ pass B: wave per dst node; gather with precomputed alphas; denom from same loop ============
__device__ __forceinline__ void aggB(const unsigned short* __restrict__ xp,
                                     const float* __restrict__ al,
                                     const long long* __restrict__ colp,
                                     const int* __restrict__ rp,
                                     int i, int c, int hh, float& ax, float& ay) {
    const int r0 = rp[i], r1 = rp[i + 1];
    float t = 0.f, ox = 0.f, oy = 0.f;
    int k = r0;
    for (; k + 2 <= r1; k += 2) {
        long long v0 = colp[k], v1 = colp[k + 1];
        int s0 = (int)(v0 & 0xFFFFFFFFll), e0 = (int)(v0 >> 32);
        int s1 = (int)(v1 & 0xFFFFFFFFll), e1 = (int)(v1 >> 32);
        float a0 = al[(size_t)e0 * 4 + hh];
        float a1 = al[(size_t)e1 * 4 + hh];
        unsigned u0 = *(const unsigned*)&xp[(size_t)s0 * 128 + c];
        unsigned u1 = *(const unsigned*)&xp[(size_t)s1 * 128 + c];
        t += a0 + a1;
        ox += a0 * __uint_as_float(u0 << 16) + a1 * __uint_as_float(u1 << 16);
        oy += a0 * __uint_as_float(u0 & 0xFFFF0000u) + a1 * __uint_as_float(u1 & 0xFFFF0000u);
    }
    if (k < r1) {
        long long v0 = colp[k];
        int s0 = (int)(v0 & 0xFFFFFFFFll), e0 = (int)(v0 >> 32);
        float a0 = al[(size_t)e0 * 4 + hh];
        unsigned u0 = *(const unsigned*)&xp[(size_t)s0 * 128 + c];
        t += a0;
        ox += a0 * __uint_as_float(u0 << 16);
        oy += a0 * __uint_as_float(u0 & 0xFFFF0000u);
    }
    {   // self-loop: raw alpha = exp(0) = 1
        unsigned u = *(const unsigned*)&xp[(size_t)i * 128 + c];
        ox += __uint_as_float(u << 16);
        oy += __uint_as_float(u & 0xFFFF0000u);
    }
    const float id = 1.f / (t + 1.f);
    ax += id * ox;
    ay += id * oy;
}

__global__ void gat_fused_kernel(const unsigned short* __restrict__ xpO, const float* __restrict__ alO,
                                 const long long* __restrict__ cpO, const int* __restrict__ rpO,
                                 const float* __restrict__ bgO,
                                 const unsigned short* __restrict__ xpS, const float* __restrict__ alS,
                                 const long long* __restrict__ cpS, const int* __restrict__ rpS,
                                 const float* __restrict__ bgS,
                                 const float* __restrict__ emb, const float* __restrict__ Wc,
                                 const float* __restrict__ bc, float* __restrict__ out, int n) {
    const int wave = threadIdx.x >> 6, lane = threadIdx.x & 63;
    const int i = blockIdx.x * 4 + wave;
    if (i >= n) return;
    const int c = lane * 2, hh = lane >> 4;

    float ax = 0.f, ay = 0.f;
    aggB(xpO, alO, cpO, rpO, i, c, hh, ax, ay);
    aggB(xpS, alS, cpS, rpS, i, c, hh, ax, ay);

    float2 e = *(const float2*)&emb[(size_t)i * 128 + c];
    float fx = e.x + ax + bgO[c] + bgS[c];
    float fy = e.y + ay + bgO[c + 1] + bgS[c + 1];

    float2 w = *(const float2*)&Wc[c];
    float p = fx * w.x + fy * w.y;
#pragma unroll
    for (int o = 32; o > 0; o >>= 1) p += __shfl_xor(p, o);
    if (lane == 0) out[i] = 1.f / (1.f + expf(-(p + bc[0])));
}

extern "C" void kernel_launch(void* const* d_in, const int* in_sizes, int n_in,
                              void* d_out, int out_size, void* d_ws, size_t ws_size,
                              hipStream_t stream) {
    const int N = NNODES, E = NEDGES;
    const float* x_acc = (const float*)d_in[0];
    const float* x_cus = (const float*)d_in[1];
    const float* x_txn = (const float*)d_in[2];
    const int* ei_owns = (const int*)d_in[4];
    const int* ei_shr = (const int*)d_in[5];
    const float* W_acc = (const float*)d_in[6];
    const float* b_acc = (const float*)d_in[7];
    const float* W_cus = (const float*)d_in[8];
    const float* b_cus = (const float*)d_in[9];
    const float* W_txn = (const float*)d_in[10];
    const float* b_txn = (const float*)d_in[11];
    const float* Wg_o = (const float*)d_in[12];
    const float* as_o = (const float*)d_in[13];
    const float* ad_o = (const float*)d_in[14];
    const float* bg_o = (const float*)d_in[15];
    const float* Wg_s = (const float*)d_in[16];
    const float* as_s = (const float*)d_in[17];
    const float* ad_s = (const float*)d_in[18];
    const float* bg_s = (const float*)d_in[19];
    const float* W_cls = (const float*)d_in[20];
    const float* b_cls = (const float*)d_in[21];
    float* out = (float*)d_out;

    float* wf = (float*)d_ws;
    int* iw = (int*)d_ws;
    float* emb = wf;                                                // [0, 6.4M) floats
    unsigned short* xp_o = (unsigned short*)(wf + 6400000);         // 6.4M bf16
    unsigned short* xp_s = (unsigned short*)(wf + 9600000);         // 6.4M bf16
    float* ss_o = wf + 12800000;                                    // 200k
    float* sd_o = wf + 13000000;
    float* ss_s = wf + 13200000;
    float* sd_s = wf + 13400000;
    float* al_o = wf + 13600000;                                    // E*4 = 2M
    float* al_s = wf + 15600000;                                    // 2M
    int* rp_o   = iw + 17600000;                                    // N+1
    int* rp_s   = iw + 17650008;
    long long* cp_o = (long long*)(iw + 17700016);                  // E u64 (byte ofs %8==0)
    long long* cp_s = (long long*)(iw + 18700016);                  // E u64
    int* counts = iw + 19700016;                                    // N
    int* cursor = iw + 19750016;                                    // N

    const int gE = (E + 255) / 256, gN = (N + 255) / 256;
    const int gT = (N + 31) / 32;       // xp_all tiles (32 rows/block)
    const int gA = (N + 3) / 4;         // aggregate (wave per node)

    // CSR for the two live edge types (src = row 0, dst = row 1); slots canonicalized by sort
    zero_int<<<gN, 256, 0, stream>>>(counts, N);
    count_kernel<<<gE, 256, 0, stream>>>(ei_owns + E, E, counts);
    scan_kernel<<<1, 1024, 0, stream>>>(counts, rp_o, cursor, N);
    scatter_pack_kernel<<<gE, 256, 0, stream>>>(ei_owns, ei_owns + E, E, cursor, cp_o);
    sort_rows_kernel<<<gN, 256, 0, stream>>>(rp_o, cp_o, N);
    zero_int<<<gN, 256, 0, stream>>>(counts, N);
    count_kernel<<<gE, 256, 0, stream>>>(ei_shr + E, E, counts);
    scan_kernel<<<1, 1024, 0, stream>>>(counts, rp_s, cursor, N);
    scatter_pack_kernel<<<gE, 256, 0, stream>>>(ei_shr, ei_shr + E, E, cursor, cp_s);
    sort_rows_kernel<<<gN, 256, 0, stream>>>(rp_s, cp_s, N);

    // per type: fused embed+xp+scores -> edge alphas -> fused aggregate+residual+classifier
    xp_all_kernel<64><<<gT, 256, 0, stream>>>(x_acc, W_acc, b_acc, Wg_o, as_o, ad_o,
                                              Wg_s, as_s, ad_s, emb, xp_o, xp_s,
                                              ss_o, sd_o, ss_s, sd_s, N);
    alpha_kernel<<<gE, 256, 0, stream>>>(ei_owns, ss_o, sd_o, al_o, E);
    alpha_kernel<<<gE, 256, 0, stream>>>(ei_shr, ss_s, sd_s, al_s, E);
    gat_fused_kernel<<<gA, 256, 0, stream>>>(xp_o, al_o, cp_o, rp_o, bg_o,
                                             xp_s, al_s, cp_s, rp_s, bg_s,
                                             emb, W_cls, b_cls, out, N);

    xp_all_kernel<32><<<gT, 256, 0, stream>>>(x_cus, W_cus, b_cus, Wg_o, as_o, ad_o,
                                              Wg_s, as_s, ad_s, emb, xp_o, xp_s,
                                              ss_o, sd_o, ss_s, sd_s, N);
    alpha_kernel<<<gE, 256, 0, stream>>>(ei_owns, ss_o, sd_o, al_o, E);
    alpha_kernel<<<gE, 256, 0, stream>>>(ei_shr, ss_s, sd_s, al_s, E);
    gat_fused_kernel<<<gA, 256, 0, stream>>>(xp_o, al_o, cp_o, rp_o, bg_o,
                                             xp_s, al_s, cp_s, rp_s, bg_s,
                                             emb, W_cls, b_cls, out + N, N);

    xp_all_kernel<128><<<gT, 256, 0, stream>>>(x_txn, W_txn, b_txn, Wg_o, as_o, ad_o,
                                               Wg_s, as_s, ad_s, emb, xp_o, xp_s,
                                               ss_o, sd_o, ss_s, sd_s, N);
    alpha_kernel<<<gE, 256, 0, stream>>>(ei_owns, ss_o, sd_o, al_o, E);
    alpha_kernel<<<gE, 256, 0, stream>>>(ei_shr, ss_s, sd_s, al_s, E);
    gat_fused_kernel<<<gA, 256, 0, stream>>>(xp_o, al_o, cp_o, rp_o, bg_o,
                                             xp_s, al_s, cp_s, rp_s, bg_s,
                                             emb, W_cls, b_cls, out + 2 * N, N);
}

// Round 15
// 711.523 us; speedup vs baseline: 1.1647x; 1.0981x over previous
//
#include <hip/hip_runtime.h>
#include <hip/hip_bf16.h>
#include <math.h>

#define NNODES 50000
#define NEDGES 500000

__device__ __forceinline__ float lrelu(float x) { return x > 0.f ? x : 0.2f * x; }

__device__ __forceinline__ unsigned short f2bf(float f) {
    unsigned int u = __float_as_uint(f);
    u += 0x7FFFu + ((u >> 16) & 1u);   // round-nearest-even
    return (unsigned short)(u >> 16);
}

// ============ per-type fused kernel: embed GEMM -> h ; h@WgO, h@WgS ; att scores ============
// R7-proven form: 32 rows x 128 cols, 256 threads, 4 rows/thread, direct global W loads.
template <int K>
__launch_bounds__(256)
__global__ void xp_all_kernel(const float* __restrict__ X,
                              const float* __restrict__ Wt, const float* __restrict__ bt,
                              const float* __restrict__ WgO, const float* __restrict__ asO,
                              const float* __restrict__ adO,
                              const float* __restrict__ WgS, const float* __restrict__ asS,
                              const float* __restrict__ adS,
                              float* __restrict__ emb,
                              unsigned short* __restrict__ xpO, unsigned short* __restrict__ xpS,
                              float* __restrict__ ssO, float* __restrict__ sdO,
                              float* __restrict__ ssS, float* __restrict__ sdS, int n) {
    __shared__ float xs[32][K];
    __shared__ float hs[32][128];
    const int t = threadIdx.x;
    const int j4 = t & 31, r = t >> 5;
    const int row0 = blockIdx.x * 32;

    constexpr int KQ = K / 4;
    for (int f = t; f < 32 * KQ; f += 256) {
        int row = f / KQ, kq = f - row * KQ;
        float4 v = {0.f, 0.f, 0.f, 0.f};
        if (row0 + row < n) v = *(const float4*)&X[(size_t)(row0 + row) * K + kq * 4];
        *(float4*)&xs[row][kq * 4] = v;
    }
    __syncthreads();

    // GEMM1: h = X @ Wt + bt
    float4 h[4];
#pragma unroll
    for (int p = 0; p < 4; p++) h[p] = {0.f, 0.f, 0.f, 0.f};
#pragma unroll 4
    for (int k = 0; k < K; k++) {
        float4 w = *(const float4*)&Wt[k * 128 + j4 * 4];
        float x0 = xs[r][k], x1 = xs[r + 8][k], x2 = xs[r + 16][k], x3 = xs[r + 24][k];
        h[0].x += x0 * w.x; h[0].y += x0 * w.y; h[0].z += x0 * w.z; h[0].w += x0 * w.w;
        h[1].x += x1 * w.x; h[1].y += x1 * w.y; h[1].z += x1 * w.z; h[1].w += x1 * w.w;
        h[2].x += x2 * w.x; h[2].y += x2 * w.y; h[2].z += x2 * w.z; h[2].w += x2 * w.w;
        h[3].x += x3 * w.x; h[3].y += x3 * w.y; h[3].z += x3 * w.z; h[3].w += x3 * w.w;
    }
    float4 bv = *(const float4*)&bt[j4 * 4];
#pragma unroll
    for (int p = 0; p < 4; p++) {
        h[p].x += bv.x; h[p].y += bv.y; h[p].z += bv.z; h[p].w += bv.w;
        int row = row0 + r + 8 * p;
        *(float4*)&hs[r + 8 * p][j4 * 4] = h[p];
        if (row < n) *(float4*)&emb[(size_t)row * 128 + j4 * 4] = h[p];
    }
    __syncthreads();

    // GEMM2: xpO = h @ WgO, xpS = h @ WgS
    float4 aO[4], aS[4];
#pragma unroll
    for (int p = 0; p < 4; p++) { aO[p] = {0.f, 0.f, 0.f, 0.f}; aS[p] = {0.f, 0.f, 0.f, 0.f}; }
#pragma unroll 2
    for (int k = 0; k < 128; k++) {
        float4 wo = *(const float4*)&WgO[k * 128 + j4 * 4];
        float4 ws = *(const float4*)&WgS[k * 128 + j4 * 4];
        float x0 = hs[r][k], x1 = hs[r + 8][k], x2 = hs[r + 16][k], x3 = hs[r + 24][k];
        aO[0].x += x0 * wo.x; aO[0].y += x0 * wo.y; aO[0].z += x0 * wo.z; aO[0].w += x0 * wo.w;
        aO[1].x += x1 * wo.x; aO[1].y += x1 * wo.y; aO[1].z += x1 * wo.z; aO[1].w += x1 * wo.w;
        aO[2].x += x2 * wo.x; aO[2].y += x2 * wo.y; aO[2].z += x2 * wo.z; aO[2].w += x2 * wo.w;
        aO[3].x += x3 * wo.x; aO[3].y += x3 * wo.y; aO[3].z += x3 * wo.z; aO[3].w += x3 * wo.w;
        aS[0].x += x0 * ws.x; aS[0].y += x0 * ws.y; aS[0].z += x0 * ws.z; aS[0].w += x0 * ws.w;
        aS[1].x += x1 * ws.x; aS[1].y += x1 * ws.y; aS[1].z += x1 * ws.z; aS[1].w += x1 * ws.w;
        aS[2].x += x2 * ws.x; aS[2].y += x2 * ws.y; aS[2].z += x2 * ws.z; aS[2].w += x2 * ws.w;
        aS[3].x += x3 * ws.x; aS[3].y += x3 * ws.y; aS[3].z += x3 * ws.z; aS[3].w += x3 * ws.w;
    }

    float4 vasO = *(const float4*)&asO[j4 * 4];
    float4 vadO = *(const float4*)&adO[j4 * 4];
    float4 vasS = *(const float4*)&asS[j4 * 4];
    float4 vadS = *(const float4*)&adS[j4 * 4];
#pragma unroll
    for (int p = 0; p < 4; p++) {
        int row = row0 + r + 8 * p;
        if (row < n) {
            ushort4 uo, us;
            uo.x = f2bf(aO[p].x); uo.y = f2bf(aO[p].y); uo.z = f2bf(aO[p].z); uo.w = f2bf(aO[p].w);
            us.x = f2bf(aS[p].x); us.y = f2bf(aS[p].y); us.z = f2bf(aS[p].z); us.w = f2bf(aS[p].w);
            *(ushort4*)&xpO[(size_t)row * 128 + j4 * 4] = uo;
            *(ushort4*)&xpS[(size_t)row * 128 + j4 * 4] = us;
        }
        float psO = aO[p].x * vasO.x + aO[p].y * vasO.y + aO[p].z * vasO.z + aO[p].w * vasO.w;
        float pdO = aO[p].x * vadO.x + aO[p].y * vadO.y + aO[p].z * vadO.z + aO[p].w * vadO.w;
        float psS = aS[p].x * vasS.x + aS[p].y * vasS.y + aS[p].z * vasS.z + aS[p].w * vasS.w;
        float pdS = aS[p].x * vadS.x + aS[p].y * vadS.y + aS[p].z * vadS.z + aS[p].w * vadS.w;
#pragma unroll
        for (int o = 4; o > 0; o >>= 1) {
            psO += __shfl_xor(psO, o);
            pdO += __shfl_xor(pdO, o);
            psS += __shfl_xor(psS, o);
            pdS += __shfl_xor(pdS, o);
        }
        if ((j4 & 7) == 0 && row < n) {
            int hidx = row * 4 + (j4 >> 3);
            ssO[hidx] = psO; sdO[hidx] = pdO;
            ssS[hidx] = psS; sdS[hidx] = pdS;
        }
    }
}

// ============ CSR build: multi-block scan (deterministic integer ops) ============
__global__ void zero_int(int* __restrict__ p, int n) {
    int i = blockIdx.x * blockDim.x + threadIdx.x;
    if (i < n) p[i] = 0;
}

__global__ void count_kernel(const int* __restrict__ dst, int e, int* __restrict__ counts) {
    int i = blockIdx.x * blockDim.x + threadIdx.x;
    if (i < e) atomicAdd(&counts[dst[i]], 1);
}

__global__ void block_sum_kernel(const int* __restrict__ counts, int n, int* __restrict__ psum) {
    __shared__ int ws[16];
    int tid = threadIdx.x, lane = tid & 63, wid = tid >> 6;
    int i = blockIdx.x * 1024 + tid;
    int v = (i < n) ? counts[i] : 0;
#pragma unroll
    for (int o = 1; o < 64; o <<= 1) v += __shfl_xor(v, o);
    if (lane == 0) ws[wid] = v;
    __syncthreads();
    if (tid < 16) {
        int s = ws[tid];
#pragma unroll
        for (int o = 1; o < 16; o <<= 1) s += __shfl_xor(s, o, 16);
        if (tid == 0) psum[blockIdx.x] = s;
    }
}

__global__ void scan_psum_kernel(int* __restrict__ psum, int nb, int* __restrict__ total) {
    int lane = threadIdx.x;   // 64 threads, nb <= 64
    int v = (lane < nb) ? psum[lane] : 0;
    int x = v;
#pragma unroll
    for (int o = 1; o < 64; o <<= 1) {
        int t = __shfl_up(x, o);
        if (lane >= o) x += t;
    }
    if (lane < nb) psum[lane] = x - v;   // exclusive
    if (lane == 63) *total = x;
}

__global__ void scan_block_kernel(const int* __restrict__ counts, const int* __restrict__ psum,
                                  int n, int* __restrict__ row_ptr, int* __restrict__ cursor) {
    __shared__ int ws[16];
    int tid = threadIdx.x, lane = tid & 63, wid = tid >> 6;
    int i = blockIdx.x * 1024 + tid;
    int v = (i < n) ? counts[i] : 0;
    int x = v;
#pragma unroll
    for (int o = 1; o < 64; o <<= 1) {
        int t = __shfl_up(x, o);
        if (lane >= o) x += t;
    }
    if (lane == 63) ws[wid] = x;
    __syncthreads();
    if (tid < 16) {
        int s = ws[tid];
#pragma unroll
        for (int o = 1; o < 16; o <<= 1) {
            int t = __shfl_up(s, o, 16);
            if (tid >= o) s += t;
        }
        ws[tid] = s;
    }
    __syncthreads();
    int base = psum[blockIdx.x] + (wid ? ws[wid - 1] : 0);
    int excl = base + x - v;
    if (i < n) { row_ptr[i] = excl; cursor[i] = excl; }
}

// scatter with packed (edge_id, src) per slot
__global__ void scatter_pack_kernel(const int* __restrict__ src, const int* __restrict__ dst, int e,
                                    int* __restrict__ cursor, long long* __restrict__ colp) {
    int i = blockIdx.x * blockDim.x + threadIdx.x;
    if (i < e) {
        int d = dst[i];
        int p = atomicAdd(&cursor[d], 1);
        colp[p] = ((long long)i << 32) | (unsigned)src[i];
    }
}

// canonicalize slot order per row (insertion sort by packed eid) -> deterministic CSR
__global__ void sort_rows_kernel(const int* __restrict__ rp, long long* __restrict__ cp, int n) {
    int i = blockIdx.x * blockDim.x + threadIdx.x;
    if (i >= n) return;
    int r0 = rp[i], r1 = rp[i + 1];
    for (int a = r0 + 1; a < r1; a++) {
        long long v = cp[a];
        int b = a - 1;
        while (b >= r0 && cp[b] > v) {
            cp[b + 1] = cp[b];
            b--;
        }
        cp[b + 1] = v;
    }
}

// ============ pass A: per-edge raw attention weights, both edge types in one launch ============
__global__ void alpha2_kernel(const int* __restrict__ eiO, const float* __restrict__ ssO,
                              const float* __restrict__ sdO, float* __restrict__ alO,
                              const int* __restrict__ eiS, const float* __restrict__ ssS,
                              const float* __restrict__ sdS, float* __restrict__ alS, int e) {
    int q = blockIdx.x * blockDim.x + threadIdx.x;
    const int* ei;
    const float* ss;
    const float* sd;
    float* al;
    int i;
    if (q < e) {
        ei = eiO; ss = ssO; sd = sdO; al = alO; i = q;
    } else {
        if (q >= 2 * e) return;
        ei = eiS; ss = ssS; sd = sdS; al = alS; i = q - e;
    }
    int s = ei[i], d = ei[e + i];
    float4 svs = *(const float4*)&ss[s * 4];
    float4 svd = *(const float4*)&ss[d * 4];
    float4 dvd = *(const float4*)&sd[d * 4];
    float4 a;
    a.x = __expf(lrelu(svs.x + dvd.x) - lrelu(svd.x + dvd.x));
    a.y = __expf(lrelu(svs.y + dvd.y) - lrelu(svd.y + dvd.y));
    a.z = __expf(lrelu(svs.z + dvd.z) - lrelu(svd.z + dvd.z));
    a.w = __expf(lrelu(svs.w + dvd.w) - lrelu(svd.w + dvd.w));
    *(float4*)&al[(size_t)i * 4] = a;
}

// ============ pass B: wave per dst node; O and S edge loops interleaved (2 indep chains) ============
__global__ void gat_fused_kernel(const unsigned short* __restrict__ xpO, const float* __restrict__ alO,
                                 const long long* __restrict__ cpO, const int* __restrict__ rpO,
                                 const float* __restrict__ bgO,
                                 const unsigned short* __restrict__ xpS, const float* __restrict__ alS,
                                 const long long* __restrict__ cpS, const int* __restrict__ rpS,
                                 const float* __restrict__ bgS,
                                 const float* __restrict__ emb, const float* __restrict__ Wc,
                                 const float* __restrict__ bc, float* __restrict__ out, int n) {
    const int wave = threadIdx.x >> 6, lane = threadIdx.x & 63;
    const int i = blockIdx.x * 4 + wave;
    if (i >= n) return;
    const int c = lane * 2, hh = lane >> 4;

    const int r0o = rpO[i], r1o = rpO[i + 1];
    const int r0s = rpS[i], r1s = rpS[i + 1];

    float tO = 0.f, oxO = 0.f, oyO = 0.f;
    float tS = 0.f, oxS = 0.f, oyS = 0.f;
    int ko = r0o, ks = r0s;

    // joint loop: two independent dependency chains per iteration
    while (ko < r1o && ks < r1s) {
        long long vo = cpO[ko], vs = cpS[ks];
        int so = (int)(vo & 0xFFFFFFFFll), eo = (int)(vo >> 32);
        int sx = (int)(vs & 0xFFFFFFFFll), es = (int)(vs >> 32);
        float ao = alO[(size_t)eo * 4 + hh];
        float as_ = alS[(size_t)es * 4 + hh];
        unsigned uo = *(const unsigned*)&xpO[(size_t)so * 128 + c];
        unsigned us = *(const unsigned*)&xpS[(size_t)sx * 128 + c];
        tO += ao;
        oxO += ao * __uint_as_float(uo << 16);
        oyO += ao * __uint_as_float(uo & 0xFFFF0000u);
        tS += as_;
        oxS += as_ * __uint_as_float(us << 16);
        oyS += as_ * __uint_as_float(us & 0xFFFF0000u);
        ko++; ks++;
    }
    for (; ko < r1o; ko++) {
        long long vo = cpO[ko];
        int so = (int)(vo & 0xFFFFFFFFll), eo = (int)(vo >> 32);
        float ao = alO[(size_t)eo * 4 + hh];
        unsigned uo = *(const unsigned*)&xpO[(size_t)so * 128 + c];
        tO += ao;
        oxO += ao * __uint_as_float(uo << 16);
        oyO += ao * __uint_as_float(uo & 0xFFFF0000u);
    }
    for (; ks < r1s; ks++) {
        long long vs = cpS[ks];
        int sx = (int)(vs & 0xFFFFFFFFll), es = (int)(vs >> 32);
        float as_ = alS[(size_t)es * 4 + hh];
        unsigned us = *(const unsigned*)&xpS[(size_t)sx * 128 + c];
        tS += as_;
        oxS += as_ * __uint_as_float(us << 16);
        oyS += as_ * __uint_as_float(us & 0xFFFF0000u);
    }
    {   // self-loops: raw alpha = exp(0) = 1
        unsigned uo = *(const unsigned*)&xpO[(size_t)i * 128 + c];
        unsigned us = *(const unsigned*)&xpS[(size_t)i * 128 + c];
        oxO += __uint_as_float(uo << 16);
        oyO += __uint_as_float(uo & 0xFFFF0000u);
        oxS += __uint_as_float(us << 16);
        oyS += __uint_as_float(us & 0xFFFF0000u);
    }
    const float idO = 1.f / (tO + 1.f), idS = 1.f / (tS + 1.f);
    float ax = idO * oxO + idS * oxS;
    float ay = idO * oyO + idS * oyS;

    float2 e = *(const float2*)&emb[(size_t)i * 128 + c];
    float fx = e.x + ax + bgO[c] + bgS[c];
    float fy = e.y + ay + bgO[c + 1] + bgS[c + 1];

    float2 w = *(const float2*)&Wc[c];
    float p = fx * w.x + fy * w.y;
#pragma unroll
    for (int o = 32; o > 0; o >>= 1) p += __shfl_xor(p, o);
    if (lane == 0) out[i] = 1.f / (1.f + expf(-(p + bc[0])));
}

extern "C" void kernel_launch(void* const* d_in, const int* in_sizes, int n_in,
                              void* d_out, int out_size, void* d_ws, size_t ws_size,
                              hipStream_t stream) {
    const int N = NNODES, E = NEDGES;
    const float* x_acc = (const float*)d_in[0];
    const float* x_cus = (const float*)d_in[1];
    const float* x_txn = (const float*)d_in[2];
    const int* ei_owns = (const int*)d_in[4];
    const int* ei_shr = (const int*)d_in[5];
    const float* W_acc = (const float*)d_in[6];
    const float* b_acc = (const float*)d_in[7];
    const float* W_cus = (const float*)d_in[8];
    const float* b_cus = (const float*)d_in[9];
    const float* W_txn = (const float*)d_in[10];
    const float* b_txn = (const float*)d_in[11];
    const float* Wg_o = (const float*)d_in[12];
    const float* as_o = (const float*)d_in[13];
    const float* ad_o = (const float*)d_in[14];
    const float* bg_o = (const float*)d_in[15];
    const float* Wg_s = (const float*)d_in[16];
    const float* as_s = (const float*)d_in[17];
    const float* ad_s = (const float*)d_in[18];
    const float* bg_s = (const float*)d_in[19];
    const float* W_cls = (const float*)d_in[20];
    const float* b_cls = (const float*)d_in[21];
    float* out = (float*)d_out;

    float* wf = (float*)d_ws;
    int* iw = (int*)d_ws;
    float* emb = wf;                                                // [0, 6.4M) floats
    unsigned short* xp_o = (unsigned short*)(wf + 6400000);         // 6.4M bf16
    unsigned short* xp_s = (unsigned short*)(wf + 9600000);         // 6.4M bf16
    float* ss_o = wf + 12800000;                                    // 200k
    float* sd_o = wf + 13000000;
    float* ss_s = wf + 13200000;
    float* sd_s = wf + 13400000;
    float* al_o = wf + 13600000;                                    // E*4 = 2M
    float* al_s = wf + 15600000;                                    // 2M
    int* rp_o   = iw + 17600000;                                    // N+1
    int* rp_s   = iw + 17650008;
    long long* cp_o = (long long*)(iw + 17700016);                  // E u64 (byte ofs %8==0)
    long long* cp_s = (long long*)(iw + 18700016);                  // E u64
    int* counts = iw + 19700016;                                    // N
    int* cursor = iw + 19750016;                                    // N
    int* psum   = iw + 19800016;                                    // 64

    const int gE = (E + 255) / 256, gN = (N + 255) / 256;
    const int gS = (N + 1023) / 1024;   // scan blocks (49)
    const int gT = (N + 31) / 32;       // xp_all tiles (32 rows/block)
    const int gA = (N + 3) / 4;         // aggregate (wave per node)
    const int gA2 = (2 * E + 255) / 256;

    // CSR for the two live edge types (src = row 0, dst = row 1); slots canonicalized by sort
    zero_int<<<gN, 256, 0, stream>>>(counts, N);
    count_kernel<<<gE, 256, 0, stream>>>(ei_owns + E, E, counts);
    block_sum_kernel<<<gS, 1024, 0, stream>>>(counts, N, psum);
    scan_psum_kernel<<<1, 64, 0, stream>>>(psum, gS, rp_o + N);
    scan_block_kernel<<<gS, 1024, 0, stream>>>(counts, psum, N, rp_o, cursor);
    scatter_pack_kernel<<<gE, 256, 0, stream>>>(ei_owns, ei_owns + E, E, cursor, cp_o);
    sort_rows_kernel<<<gN, 256, 0, stream>>>(rp_o, cp_o, N);
    zero_int<<<gN, 256, 0, stream>>>(counts, N);
    count_kernel<<<gE, 256, 0, stream>>>(ei_shr + E, E, counts);
    block_sum_kernel<<<gS, 1024, 0, stream>>>(counts, N, psum);
    scan_psum_kernel<<<1, 64, 0, stream>>>(psum, gS, rp_s + N);
    scan_block_kernel<<<gS, 1024, 0, stream>>>(counts, psum, N, rp_s, cursor);
    scatter_pack_kernel<<<gE, 256, 0, stream>>>(ei_shr, ei_shr + E, E, cursor, cp_s);
    sort_rows_kernel<<<gN, 256, 0, stream>>>(rp_s, cp_s, N);

    // per type: fused embed+xp+scores -> edge alphas (both types, one launch) -> fused aggregate
    xp_all_kernel<64><<<gT, 256, 0, stream>>>(x_acc, W_acc, b_acc, Wg_o, as_o, ad_o,
                                              Wg_s, as_s, ad_s, emb, xp_o, xp_s,
                                              ss_o, sd_o, ss_s, sd_s, N);
    alpha2_kernel<<<gA2, 256, 0, stream>>>(ei_owns, ss_o, sd_o, al_o,
                                           ei_shr, ss_s, sd_s, al_s, E);
    gat_fused_kernel<<<gA, 256, 0, stream>>>(xp_o, al_o, cp_o, rp_o, bg_o,
                                             xp_s, al_s, cp_s, rp_s, bg_s,
                                             emb, W_cls, b_cls, out, N);

    xp_all_kernel<32><<<gT, 256, 0, stream>>>(x_cus, W_cus, b_cus, Wg_o, as_o, ad_o,
                                              Wg_s, as_s, ad_s, emb, xp_o, xp_s,
                                              ss_o, sd_o, ss_s, sd_s, N);
    alpha2_kernel<<<gA2, 256, 0, stream>>>(ei_owns, ss_o, sd_o, al_o,
                                           ei_shr, ss_s, sd_s, al_s, E);
    gat_fused_kernel<<<gA, 256, 0, stream>>>(xp_o, al_o, cp_o, rp_o, bg_o,
                                             xp_s, al_s, cp_s, rp_s, bg_s,
                                             emb, W_cls, b_cls, out + N, N);

    xp_all_kernel<128><<<gT, 256, 0, stream>>>(x_txn, W_txn, b_txn, Wg_o, as_o, ad_o,
                                               Wg_s, as_s, ad_s, emb, xp_o, xp_s,
                                               ss_o, sd_o, ss_s, sd_s, N);
    alpha2_kernel<<<gA2, 256, 0, stream>>>(ei_owns, ss_o, sd_o, al_o,
                                           ei_shr, ss_s, sd_s, al_s, E);
    gat_fused_kernel<<<gA, 256, 0, stream>>>(xp_o, al_o, cp_o, rp_o, bg_o,
                                             xp_s, al_s, cp_s, rp_s, bg_s,
                                             emb, W_cls, b_cls, out + 2 * N, N);
}

// Round 16
// 653.224 us; speedup vs baseline: 1.2686x; 1.0892x over previous
//
#include <hip/hip_runtime.h>
#include <hip/hip_bf16.h>
#include <math.h>

#define NNODES 50000
#define NEDGES 500000
#define NTILES 1563   // (NNODES+31)/32

__device__ __forceinline__ float lrelu(float x) { return x > 0.f ? x : 0.2f * x; }

__device__ __forceinline__ unsigned short f2bf(float f) {
    unsigned int u = __float_as_uint(f);
    u += 0x7FFFu + ((u >> 16) & 1u);   // round-nearest-even
    return (unsigned short)(u >> 16);
}

// ============ batched per-type fused kernel: embed GEMM -> h ; h@WgO/WgS ; scores ; h.Wc ============
// grid = 3*NTILES; type = blockIdx.x / NTILES. 32 rows x 128 cols, 256 threads, 4 rows/thread.
// Writes embPart = h.Wc (scalar/row) instead of the 128-dim emb row (classifier linearity).
__launch_bounds__(256)
__global__ void xp_all_b(const float* __restrict__ X0, const float* __restrict__ X1,
                         const float* __restrict__ X2,
                         const float* __restrict__ Wt0, const float* __restrict__ bt0,
                         const float* __restrict__ Wt1, const float* __restrict__ bt1,
                         const float* __restrict__ Wt2, const float* __restrict__ bt2,
                         const float* __restrict__ WgO, const float* __restrict__ asO,
                         const float* __restrict__ adO,
                         const float* __restrict__ WgS, const float* __restrict__ asS,
                         const float* __restrict__ adS,
                         const float* __restrict__ Wc,
                         float* __restrict__ embPart,
                         unsigned short* __restrict__ xpO, unsigned short* __restrict__ xpS,
                         float* __restrict__ ssO, float* __restrict__ sdO,
                         float* __restrict__ ssS, float* __restrict__ sdS, int n) {
    __shared__ float xs[32][128];
    __shared__ float hs[32][128];
    const int t = threadIdx.x;
    const int j4 = t & 31, r = t >> 5;
    const int tile = blockIdx.x % NTILES;
    const int type = blockIdx.x / NTILES;
    const int row0 = tile * 32;

    const float* X;
    const float* Wt;
    const float* bt;
    int K, ksh;
    if (type == 0)      { X = X0; Wt = Wt0; bt = bt0; K = 64;  ksh = 4; }
    else if (type == 1) { X = X1; Wt = Wt1; bt = bt1; K = 32;  ksh = 3; }
    else                { X = X2; Wt = Wt2; bt = bt2; K = 128; ksh = 5; }
    const size_t tb = (size_t)type * n;

    const int KQ = K >> 2;
    for (int f = t; f < 32 * KQ; f += 256) {
        int row = f >> ksh, kq = f & (KQ - 1);
        float4 v = {0.f, 0.f, 0.f, 0.f};
        if (row0 + row < n) v = *(const float4*)&X[(size_t)(row0 + row) * K + kq * 4];
        *(float4*)&xs[row][kq * 4] = v;
    }
    __syncthreads();

    // GEMM1: h = X @ Wt + bt (runtime K)
    float4 h[4];
#pragma unroll
    for (int p = 0; p < 4; p++) h[p] = {0.f, 0.f, 0.f, 0.f};
#pragma unroll 4
    for (int k = 0; k < K; k++) {
        float4 w = *(const float4*)&Wt[k * 128 + j4 * 4];
        float x0 = xs[r][k], x1 = xs[r + 8][k], x2 = xs[r + 16][k], x3 = xs[r + 24][k];
        h[0].x += x0 * w.x; h[0].y += x0 * w.y; h[0].z += x0 * w.z; h[0].w += x0 * w.w;
        h[1].x += x1 * w.x; h[1].y += x1 * w.y; h[1].z += x1 * w.z; h[1].w += x1 * w.w;
        h[2].x += x2 * w.x; h[2].y += x2 * w.y; h[2].z += x2 * w.z; h[2].w += x2 * w.w;
        h[3].x += x3 * w.x; h[3].y += x3 * w.y; h[3].z += x3 * w.z; h[3].w += x3 * w.w;
    }
    float4 bv = *(const float4*)&bt[j4 * 4];
    float4 wc = *(const float4*)&Wc[j4 * 4];
#pragma unroll
    for (int p = 0; p < 4; p++) {
        h[p].x += bv.x; h[p].y += bv.y; h[p].z += bv.z; h[p].w += bv.w;
        int row = row0 + r + 8 * p;
        *(float4*)&hs[r + 8 * p][j4 * 4] = h[p];
        // embPart = h . Wc (reduce over the 32 j4-lanes of this row)
        float dp = h[p].x * wc.x + h[p].y * wc.y + h[p].z * wc.z + h[p].w * wc.w;
#pragma unroll
        for (int o = 16; o > 0; o >>= 1) dp += __shfl_xor(dp, o);
        if (j4 == 0 && row < n) embPart[tb + row] = dp;
    }
    __syncthreads();

    // GEMM2: xpO = h @ WgO, xpS = h @ WgS
    float4 aO[4], aS[4];
#pragma unroll
    for (int p = 0; p < 4; p++) { aO[p] = {0.f, 0.f, 0.f, 0.f}; aS[p] = {0.f, 0.f, 0.f, 0.f}; }
#pragma unroll 2
    for (int k = 0; k < 128; k++) {
        float4 wo = *(const float4*)&WgO[k * 128 + j4 * 4];
        float4 ws = *(const float4*)&WgS[k * 128 + j4 * 4];
        float x0 = hs[r][k], x1 = hs[r + 8][k], x2 = hs[r + 16][k], x3 = hs[r + 24][k];
        aO[0].x += x0 * wo.x; aO[0].y += x0 * wo.y; aO[0].z += x0 * wo.z; aO[0].w += x0 * wo.w;
        aO[1].x += x1 * wo.x; aO[1].y += x1 * wo.y; aO[1].z += x1 * wo.z; aO[1].w += x1 * wo.w;
        aO[2].x += x2 * wo.x; aO[2].y += x2 * wo.y; aO[2].z += x2 * wo.z; aO[2].w += x2 * wo.w;
        aO[3].x += x3 * wo.x; aO[3].y += x3 * wo.y; aO[3].z += x3 * wo.z; aO[3].w += x3 * wo.w;
        aS[0].x += x0 * ws.x; aS[0].y += x0 * ws.y; aS[0].z += x0 * ws.z; aS[0].w += x0 * ws.w;
        aS[1].x += x1 * ws.x; aS[1].y += x1 * ws.y; aS[1].z += x1 * ws.z; aS[1].w += x1 * ws.w;
        aS[2].x += x2 * ws.x; aS[2].y += x2 * ws.y; aS[2].z += x2 * ws.z; aS[2].w += x2 * ws.w;
        aS[3].x += x3 * ws.x; aS[3].y += x3 * ws.y; aS[3].z += x3 * ws.z; aS[3].w += x3 * ws.w;
    }

    float4 vasO = *(const float4*)&asO[j4 * 4];
    float4 vadO = *(const float4*)&adO[j4 * 4];
    float4 vasS = *(const float4*)&asS[j4 * 4];
    float4 vadS = *(const float4*)&adS[j4 * 4];
#pragma unroll
    for (int p = 0; p < 4; p++) {
        int row = row0 + r + 8 * p;
        if (row < n) {
            ushort4 uo, us;
            uo.x = f2bf(aO[p].x); uo.y = f2bf(aO[p].y); uo.z = f2bf(aO[p].z); uo.w = f2bf(aO[p].w);
            us.x = f2bf(aS[p].x); us.y = f2bf(aS[p].y); us.z = f2bf(aS[p].z); us.w = f2bf(aS[p].w);
            *(ushort4*)&xpO[(tb + row) * 128 + j4 * 4] = uo;
            *(ushort4*)&xpS[(tb + row) * 128 + j4 * 4] = us;
        }
        float psO = aO[p].x * vasO.x + aO[p].y * vasO.y + aO[p].z * vasO.z + aO[p].w * vasO.w;
        float pdO = aO[p].x * vadO.x + aO[p].y * vadO.y + aO[p].z * vadO.z + aO[p].w * vadO.w;
        float psS = aS[p].x * vasS.x + aS[p].y * vasS.y + aS[p].z * vasS.z + aS[p].w * vasS.w;
        float pdS = aS[p].x * vadS.x + aS[p].y * vadS.y + aS[p].z * vadS.z + aS[p].w * vadS.w;
#pragma unroll
        for (int o = 4; o > 0; o >>= 1) {
            psO += __shfl_xor(psO, o);
            pdO += __shfl_xor(pdO, o);
            psS += __shfl_xor(psS, o);
            pdS += __shfl_xor(pdS, o);
        }
        if ((j4 & 7) == 0 && row < n) {
            size_t hidx = (tb + row) * 4 + (j4 >> 3);
            ssO[hidx] = psO; sdO[hidx] = pdO;
            ssS[hidx] = psS; sdS[hidx] = pdS;
        }
    }
}

// ============ CSR build: multi-block scan (deterministic integer ops) ============
__global__ void zero_int(int* __restrict__ p, int n) {
    int i = blockIdx.x * blockDim.x + threadIdx.x;
    if (i < n) p[i] = 0;
}

__global__ void count_kernel(const int* __restrict__ dst, int e, int* __restrict__ counts) {
    int i = blockIdx.x * blockDim.x + threadIdx.x;
    if (i < e) atomicAdd(&counts[dst[i]], 1);
}

__global__ void block_sum_kernel(const int* __restrict__ counts, int n, int* __restrict__ psum) {
    __shared__ int ws[16];
    int tid = threadIdx.x, lane = tid & 63, wid = tid >> 6;
    int i = blockIdx.x * 1024 + tid;
    int v = (i < n) ? counts[i] : 0;
#pragma unroll
    for (int o = 1; o < 64; o <<= 1) v += __shfl_xor(v, o);
    if (lane == 0) ws[wid] = v;
    __syncthreads();
    if (tid < 16) {
        int s = ws[tid];
#pragma unroll
        for (int o = 1; o < 16; o <<= 1) s += __shfl_xor(s, o, 16);
        if (tid == 0) psum[blockIdx.x] = s;
    }
}

__global__ void scan_psum_kernel(int* __restrict__ psum, int nb, int* __restrict__ total) {
    int lane = threadIdx.x;   // 64 threads, nb <= 64
    int v = (lane < nb) ? psum[lane] : 0;
    int x = v;
#pragma unroll
    for (int o = 1; o < 64; o <<= 1) {
        int t = __shfl_up(x, o);
        if (lane >= o) x += t;
    }
    if (lane < nb) psum[lane] = x - v;   // exclusive
    if (lane == 63) *total = x;
}

__global__ void scan_block_kernel(const int* __restrict__ counts, const int* __restrict__ psum,
                                  int n, int* __restrict__ row_ptr, int* __restrict__ cursor) {
    __shared__ int ws[16];
    int tid = threadIdx.x, lane = tid & 63, wid = tid >> 6;
    int i = blockIdx.x * 1024 + tid;
    int v = (i < n) ? counts[i] : 0;
    int x = v;
#pragma unroll
    for (int o = 1; o < 64; o <<= 1) {
        int t = __shfl_up(x, o);
        if (lane >= o) x += t;
    }
    if (lane == 63) ws[wid] = x;
    __syncthreads();
    if (tid < 16) {
        int s = ws[tid];
#pragma unroll
        for (int o = 1; o < 16; o <<= 1) {
            int t = __shfl_up(s, o, 16);
            if (tid >= o) s += t;
        }
        ws[tid] = s;
    }
    __syncthreads();
    int base = psum[blockIdx.x] + (wid ? ws[wid - 1] : 0);
    int excl = base + x - v;
    if (i < n) { row_ptr[i] = excl; cursor[i] = excl; }
}

__global__ void scatter_pack_kernel(const int* __restrict__ src, const int* __restrict__ dst, int e,
                                    int* __restrict__ cursor, long long* __restrict__ colp) {
    int i = blockIdx.x * blockDim.x + threadIdx.x;
    if (i < e) {
        int d = dst[i];
        int p = atomicAdd(&cursor[d], 1);
        colp[p] = ((long long)i << 32) | (unsigned)src[i];
    }
}

// canonicalize slot order per row -> deterministic CSR
__global__ void sort_rows_kernel(const int* __restrict__ rp, long long* __restrict__ cp, int n) {
    int i = blockIdx.x * blockDim.x + threadIdx.x;
    if (i >= n) return;
    int r0 = rp[i], r1 = rp[i + 1];
    for (int a = r0 + 1; a < r1; a++) {
        long long v = cp[a];
        int b = a - 1;
        while (b >= r0 && cp[b] > v) {
            cp[b + 1] = cp[b];
            b--;
        }
        cp[b + 1] = v;
    }
}

// ============ pass A: per-edge raw attention weights, all (type, conv) in one launch ============
__global__ void alpha6_kernel(const int* __restrict__ eiO, const int* __restrict__ eiS,
                              const float* __restrict__ ssO, const float* __restrict__ sdO,
                              const float* __restrict__ ssS, const float* __restrict__ sdS,
                              float* __restrict__ alO, float* __restrict__ alS, int e, int n) {
    int q = blockIdx.x * blockDim.x + threadIdx.x;
    if (q >= 6 * e) return;
    int ty = q / (2 * e);
    int rem = q - ty * 2 * e;
    const size_t nb = (size_t)ty * n * 4;
    const size_t eb = (size_t)ty * e * 4;
    const int* ei;
    const float* ss;
    const float* sd;
    float* al;
    int i;
    if (rem < e) { ei = eiO; ss = ssO + nb; sd = sdO + nb; al = alO + eb; i = rem; }
    else         { ei = eiS; ss = ssS + nb; sd = sdS + nb; al = alS + eb; i = rem - e; }
    int s = ei[i], d = ei[e + i];
    float4 svs = *(const float4*)&ss[s * 4];
    float4 svd = *(const float4*)&ss[d * 4];
    float4 dvd = *(const float4*)&sd[d * 4];
    float4 a;
    a.x = __expf(lrelu(svs.x + dvd.x) - lrelu(svd.x + dvd.x));
    a.y = __expf(lrelu(svs.y + dvd.y) - lrelu(svd.y + dvd.y));
    a.z = __expf(lrelu(svs.z + dvd.z) - lrelu(svd.z + dvd.z));
    a.w = __expf(lrelu(svs.w + dvd.w) - lrelu(svd.w + dvd.w));
    *(float4*)&al[(size_t)i * 4] = a;
}

// ============ pass B batched: wave per (type, dst node); O/S loops interleaved; + embPart ============
__global__ void gat_fused_b(const unsigned short* __restrict__ xpO, const float* __restrict__ alO,
                            const long long* __restrict__ cpO, const int* __restrict__ rpO,
                            const float* __restrict__ bgO,
                            const unsigned short* __restrict__ xpS, const float* __restrict__ alS,
                            const long long* __restrict__ cpS, const int* __restrict__ rpS,
                            const float* __restrict__ bgS,
                            const float* __restrict__ embPart, const float* __restrict__ Wc,
                            const float* __restrict__ bc, float* __restrict__ out, int n) {
    const int wave = threadIdx.x >> 6, lane = threadIdx.x & 63;
    const int i3 = blockIdx.x * 4 + wave;
    if (i3 >= 3 * n) return;
    const int ty = i3 / n, i = i3 - ty * n;
    const int c = lane * 2, hh = lane >> 4;

    const unsigned short* xo = xpO + (size_t)ty * n * 128;
    const unsigned short* xs_ = xpS + (size_t)ty * n * 128;
    const float* alo = alO + (size_t)ty * NEDGES * 4;
    const float* als = alS + (size_t)ty * NEDGES * 4;

    const int r0o = rpO[i], r1o = rpO[i + 1];
    const int r0s = rpS[i], r1s = rpS[i + 1];

    float tO = 0.f, oxO = 0.f, oyO = 0.f;
    float tS = 0.f, oxS = 0.f, oyS = 0.f;
    int ko = r0o, ks = r0s;

    while (ko < r1o && ks < r1s) {
        long long vo = cpO[ko], vs = cpS[ks];
        int so = (int)(vo & 0xFFFFFFFFll), eo = (int)(vo >> 32);
        int sx = (int)(vs & 0xFFFFFFFFll), es = (int)(vs >> 32);
        float ao = alo[(size_t)eo * 4 + hh];
        float as_ = als[(size_t)es * 4 + hh];
        unsigned uo = *(const unsigned*)&xo[(size_t)so * 128 + c];
        unsigned us = *(const unsigned*)&xs_[(size_t)sx * 128 + c];
        tO += ao;
        oxO += ao * __uint_as_float(uo << 16);
        oyO += ao * __uint_as_float(uo & 0xFFFF0000u);
        tS += as_;
        oxS += as_ * __uint_as_float(us << 16);
        oyS += as_ * __uint_as_float(us & 0xFFFF0000u);
        ko++; ks++;
    }
    for (; ko < r1o; ko++) {
        long long vo = cpO[ko];
        int so = (int)(vo & 0xFFFFFFFFll), eo = (int)(vo >> 32);
        float ao = alo[(size_t)eo * 4 + hh];
        unsigned uo = *(const unsigned*)&xo[(size_t)so * 128 + c];
        tO += ao;
        oxO += ao * __uint_as_float(uo << 16);
        oyO += ao * __uint_as_float(uo & 0xFFFF0000u);
    }
    for (; ks < r1s; ks++) {
        long long vs = cpS[ks];
        int sx = (int)(vs & 0xFFFFFFFFll), es = (int)(vs >> 32);
        float as_ = als[(size_t)es * 4 + hh];
        unsigned us = *(const unsigned*)&xs_[(size_t)sx * 128 + c];
        tS += as_;
        oxS += as_ * __uint_as_float(us << 16);
        oyS += as_ * __uint_as_float(us & 0xFFFF0000u);
    }
    {   // self-loops: raw alpha = exp(0) = 1
        unsigned uo = *(const unsigned*)&xo[(size_t)i * 128 + c];
        unsigned us = *(const unsigned*)&xs_[(size_t)i * 128 + c];
        oxO += __uint_as_float(uo << 16);
        oyO += __uint_as_float(uo & 0xFFFF0000u);
        oxS += __uint_as_float(us << 16);
        oyS += __uint_as_float(us & 0xFFFF0000u);
    }
    const float idO = 1.f / (tO + 1.f), idS = 1.f / (tS + 1.f);
    float fx = idO * oxO + idS * oxS + bgO[c] + bgS[c];
    float fy = idO * oyO + idS * oyS + bgO[c + 1] + bgS[c + 1];

    float2 w = *(const float2*)&Wc[c];
    float p = fx * w.x + fy * w.y;
#pragma unroll
    for (int o = 32; o > 0; o >>= 1) p += __shfl_xor(p, o);
    if (lane == 0) out[i3] = 1.f / (1.f + expf(-(p + embPart[i3] + bc[0])));
}

extern "C" void kernel_launch(void* const* d_in, const int* in_sizes, int n_in,
                              void* d_out, int out_size, void* d_ws, size_t ws_size,
                              hipStream_t stream) {
    const int N = NNODES, E = NEDGES;
    const float* x_acc = (const float*)d_in[0];
    const float* x_cus = (const float*)d_in[1];
    const float* x_txn = (const float*)d_in[2];
    const int* ei_owns = (const int*)d_in[4];
    const int* ei_shr = (const int*)d_in[5];
    const float* W_acc = (const float*)d_in[6];
    const float* b_acc = (const float*)d_in[7];
    const float* W_cus = (const float*)d_in[8];
    const float* b_cus = (const float*)d_in[9];
    const float* W_txn = (const float*)d_in[10];
    const float* b_txn = (const float*)d_in[11];
    const float* Wg_o = (const float*)d_in[12];
    const float* as_o = (const float*)d_in[13];
    const float* ad_o = (const float*)d_in[14];
    const float* bg_o = (const float*)d_in[15];
    const float* Wg_s = (const float*)d_in[16];
    const float* as_s = (const float*)d_in[17];
    const float* ad_s = (const float*)d_in[18];
    const float* bg_s = (const float*)d_in[19];
    const float* W_cls = (const float*)d_in[20];
    const float* b_cls = (const float*)d_in[21];
    float* out = (float*)d_out;

    float* wf = (float*)d_ws;
    int* iw = (int*)d_ws;
    // batched layout (all 3 types resident):
    unsigned short* xp_o3 = (unsigned short*)(wf + 0);          // 3N*128 bf16 = 9.6M f
    unsigned short* xp_s3 = (unsigned short*)(wf + 9600000);    // 9.6M f
    float* ss_o3 = wf + 19200000;                               // 3N*4 = 600k
    float* sd_o3 = wf + 19800000;
    float* ss_s3 = wf + 20400000;
    float* sd_s3 = wf + 21000000;
    float* al_o3 = wf + 21600000;                               // 3E*4 = 6M
    float* al_s3 = wf + 27600000;                               // 6M
    float* embPart = wf + 33600000;                             // 3N = 150k
    int* rp_o   = iw + 33750000;                                // N+1
    int* rp_s   = iw + 33800048;
    long long* cp_o = (long long*)(iw + 33850096);              // E u64 (even int ofs)
    long long* cp_s = (long long*)(iw + 34850096);              // E u64
    int* counts = iw + 35850096;                                // N
    int* cursor = iw + 35900096;                                // N
    int* psum   = iw + 35950096;                                // 64

    const int gE = (E + 255) / 256, gN = (N + 255) / 256;
    const int gS = (N + 1023) / 1024;       // scan blocks (49)
    const int gXP = 3 * NTILES;             // batched xp tiles
    const int gA = (3 * N + 3) / 4;         // batched aggregate (wave per type,node)
    const int gA6 = (6 * E + 255) / 256;    // batched alpha

    // CSR for the two live edge types (src = row 0, dst = row 1); slots canonicalized by sort
    zero_int<<<gN, 256, 0, stream>>>(counts, N);
    count_kernel<<<gE, 256, 0, stream>>>(ei_owns + E, E, counts);
    block_sum_kernel<<<gS, 1024, 0, stream>>>(counts, N, psum);
    scan_psum_kernel<<<1, 64, 0, stream>>>(psum, gS, rp_o + N);
    scan_block_kernel<<<gS, 1024, 0, stream>>>(counts, psum, N, rp_o, cursor);
    scatter_pack_kernel<<<gE, 256, 0, stream>>>(ei_owns, ei_owns + E, E, cursor, cp_o);
    sort_rows_kernel<<<gN, 256, 0, stream>>>(rp_o, cp_o, N);
    zero_int<<<gN, 256, 0, stream>>>(counts, N);
    count_kernel<<<gE, 256, 0, stream>>>(ei_shr + E, E, counts);
    block_sum_kernel<<<gS, 1024, 0, stream>>>(counts, N, psum);
    scan_psum_kernel<<<1, 64, 0, stream>>>(psum, gS, rp_s + N);
    scan_block_kernel<<<gS, 1024, 0, stream>>>(counts, psum, N, rp_s, cursor);
    scatter_pack_kernel<<<gE, 256, 0, stream>>>(ei_shr, ei_shr + E, E, cursor, cp_s);
    sort_rows_kernel<<<gN, 256, 0, stream>>>(rp_s, cp_s, N);

    // batched: all 3 types in one xp launch -> one alpha launch -> one aggregate launch
    xp_all_b<<<gXP, 256, 0, stream>>>(x_acc, x_cus, x_txn,
                                      W_acc, b_acc, W_cus, b_cus, W_txn, b_txn,
                                      Wg_o, as_o, ad_o, Wg_s, as_s, ad_s, W_cls,
                                      embPart, xp_o3, xp_s3,
                                      ss_o3, sd_o3, ss_s3, sd_s3, N);
    alpha6_kernel<<<gA6, 256, 0, stream>>>(ei_owns, ei_shr,
                                           ss_o3, sd_o3, ss_s3, sd_s3,
                                           al_o3, al_s3, E, N);
    gat_fused_b<<<gA, 256, 0, stream>>>(xp_o3, al_o3, cp_o, rp_o, bg_o,
                                        xp_s3, al_s3, cp_s, rp_s, bg_s,
                                        embPart, W_cls, b_cls, out, N);
}

// Round 17
// 605.738 us; speedup vs baseline: 1.3681x; 1.0784x over previous
//
#include <hip/hip_runtime.h>
#include <hip/hip_bf16.h>
#include <math.h>

#define NNODES 50000
#define NEDGES 500000
#define NTILES 1563   // (NNODES+31)/32

__device__ __forceinline__ float lrelu(float x) { return x > 0.f ? x : 0.2f * x; }

__device__ __forceinline__ unsigned short f2bf(float f) {
    unsigned int u = __float_as_uint(f);
    u += 0x7FFFu + ((u >> 16) & 1u);   // round-nearest-even
    return (unsigned short)(u >> 16);
}

// ============ batched per-type fused kernel: embed GEMM -> h ; h@WgO/WgS ; scores ; h.Wc ============
__launch_bounds__(256)
__global__ void xp_all_b(const float* __restrict__ X0, const float* __restrict__ X1,
                         const float* __restrict__ X2,
                         const float* __restrict__ Wt0, const float* __restrict__ bt0,
                         const float* __restrict__ Wt1, const float* __restrict__ bt1,
                         const float* __restrict__ Wt2, const float* __restrict__ bt2,
                         const float* __restrict__ WgO, const float* __restrict__ asO,
                         const float* __restrict__ adO,
                         const float* __restrict__ WgS, const float* __restrict__ asS,
                         const float* __restrict__ adS,
                         const float* __restrict__ Wc,
                         float* __restrict__ embPart,
                         unsigned short* __restrict__ xpO, unsigned short* __restrict__ xpS,
                         float* __restrict__ ssO, float* __restrict__ sdO,
                         float* __restrict__ ssS, float* __restrict__ sdS, int n) {
    __shared__ float xs[32][128];
    __shared__ float hs[32][128];
    const int t = threadIdx.x;
    const int j4 = t & 31, r = t >> 5;
    const int tile = blockIdx.x % NTILES;
    const int type = blockIdx.x / NTILES;
    const int row0 = tile * 32;

    const float* X;
    const float* Wt;
    const float* bt;
    int K, ksh;
    if (type == 0)      { X = X0; Wt = Wt0; bt = bt0; K = 64;  ksh = 4; }
    else if (type == 1) { X = X1; Wt = Wt1; bt = bt1; K = 32;  ksh = 3; }
    else                { X = X2; Wt = Wt2; bt = bt2; K = 128; ksh = 5; }
    const size_t tb = (size_t)type * n;

    const int KQ = K >> 2;
    for (int f = t; f < 32 * KQ; f += 256) {
        int row = f >> ksh, kq = f & (KQ - 1);
        float4 v = {0.f, 0.f, 0.f, 0.f};
        if (row0 + row < n) v = *(const float4*)&X[(size_t)(row0 + row) * K + kq * 4];
        *(float4*)&xs[row][kq * 4] = v;
    }
    __syncthreads();

    // GEMM1: h = X @ Wt + bt (runtime K)
    float4 h[4];
#pragma unroll
    for (int p = 0; p < 4; p++) h[p] = {0.f, 0.f, 0.f, 0.f};
#pragma unroll 4
    for (int k = 0; k < K; k++) {
        float4 w = *(const float4*)&Wt[k * 128 + j4 * 4];
        float x0 = xs[r][k], x1 = xs[r + 8][k], x2 = xs[r + 16][k], x3 = xs[r + 24][k];
        h[0].x += x0 * w.x; h[0].y += x0 * w.y; h[0].z += x0 * w.z; h[0].w += x0 * w.w;
        h[1].x += x1 * w.x; h[1].y += x1 * w.y; h[1].z += x1 * w.z; h[1].w += x1 * w.w;
        h[2].x += x2 * w.x; h[2].y += x2 * w.y; h[2].z += x2 * w.z; h[2].w += x2 * w.w;
        h[3].x += x3 * w.x; h[3].y += x3 * w.y; h[3].z += x3 * w.z; h[3].w += x3 * w.w;
    }
    float4 bv = *(const float4*)&bt[j4 * 4];
    float4 wc = *(const float4*)&Wc[j4 * 4];
#pragma unroll
    for (int p = 0; p < 4; p++) {
        h[p].x += bv.x; h[p].y += bv.y; h[p].z += bv.z; h[p].w += bv.w;
        int row = row0 + r + 8 * p;
        *(float4*)&hs[r + 8 * p][j4 * 4] = h[p];
        float dp = h[p].x * wc.x + h[p].y * wc.y + h[p].z * wc.z + h[p].w * wc.w;
#pragma unroll
        for (int o = 16; o > 0; o >>= 1) dp += __shfl_xor(dp, o);
        if (j4 == 0 && row < n) embPart[tb + row] = dp;
    }
    __syncthreads();

    // GEMM2: xpO = h @ WgO, xpS = h @ WgS
    float4 aO[4], aS[4];
#pragma unroll
    for (int p = 0; p < 4; p++) { aO[p] = {0.f, 0.f, 0.f, 0.f}; aS[p] = {0.f, 0.f, 0.f, 0.f}; }
#pragma unroll 2
    for (int k = 0; k < 128; k++) {
        float4 wo = *(const float4*)&WgO[k * 128 + j4 * 4];
        float4 ws = *(const float4*)&WgS[k * 128 + j4 * 4];
        float x0 = hs[r][k], x1 = hs[r + 8][k], x2 = hs[r + 16][k], x3 = hs[r + 24][k];
        aO[0].x += x0 * wo.x; aO[0].y += x0 * wo.y; aO[0].z += x0 * wo.z; aO[0].w += x0 * wo.w;
        aO[1].x += x1 * wo.x; aO[1].y += x1 * wo.y; aO[1].z += x1 * wo.z; aO[1].w += x1 * wo.w;
        aO[2].x += x2 * wo.x; aO[2].y += x2 * wo.y; aO[2].z += x2 * wo.z; aO[2].w += x2 * wo.w;
        aO[3].x += x3 * wo.x; aO[3].y += x3 * wo.y; aO[3].z += x3 * wo.z; aO[3].w += x3 * wo.w;
        aS[0].x += x0 * ws.x; aS[0].y += x0 * ws.y; aS[0].z += x0 * ws.z; aS[0].w += x0 * ws.w;
        aS[1].x += x1 * ws.x; aS[1].y += x1 * ws.y; aS[1].z += x1 * ws.z; aS[1].w += x1 * ws.w;
        aS[2].x += x2 * ws.x; aS[2].y += x2 * ws.y; aS[2].z += x2 * ws.z; aS[2].w += x2 * ws.w;
        aS[3].x += x3 * ws.x; aS[3].y += x3 * ws.y; aS[3].z += x3 * ws.z; aS[3].w += x3 * ws.w;
    }

    float4 vasO = *(const float4*)&asO[j4 * 4];
    float4 vadO = *(const float4*)&adO[j4 * 4];
    float4 vasS = *(const float4*)&asS[j4 * 4];
    float4 vadS = *(const float4*)&adS[j4 * 4];
#pragma unroll
    for (int p = 0; p < 4; p++) {
        int row = row0 + r + 8 * p;
        if (row < n) {
            ushort4 uo, us;
            uo.x = f2bf(aO[p].x); uo.y = f2bf(aO[p].y); uo.z = f2bf(aO[p].z); uo.w = f2bf(aO[p].w);
            us.x = f2bf(aS[p].x); us.y = f2bf(aS[p].y); us.z = f2bf(aS[p].z); us.w = f2bf(aS[p].w);
            *(ushort4*)&xpO[(tb + row) * 128 + j4 * 4] = uo;
            *(ushort4*)&xpS[(tb + row) * 128 + j4 * 4] = us;
        }
        float psO = aO[p].x * vasO.x + aO[p].y * vasO.y + aO[p].z * vasO.z + aO[p].w * vasO.w;
        float pdO = aO[p].x * vadO.x + aO[p].y * vadO.y + aO[p].z * vadO.z + aO[p].w * vadO.w;
        float psS = aS[p].x * vasS.x + aS[p].y * vasS.y + aS[p].z * vasS.z + aS[p].w * vasS.w;
        float pdS = aS[p].x * vadS.x + aS[p].y * vadS.y + aS[p].z * vadS.z + aS[p].w * vadS.w;
#pragma unroll
        for (int o = 4; o > 0; o >>= 1) {
            psO += __shfl_xor(psO, o);
            pdO += __shfl_xor(pdO, o);
            psS += __shfl_xor(psS, o);
            pdS += __shfl_xor(pdS, o);
        }
        if ((j4 & 7) == 0 && row < n) {
            size_t hidx = (tb + row) * 4 + (j4 >> 3);
            ssO[hidx] = psO; sdO[hidx] = pdO;
            ssS[hidx] = psS; sdS[hidx] = pdS;
        }
    }
}

// ============ CSR build, both edge types batched: counts2[2N], rp2[2N+1], cp2[2E] ============
__global__ void zero_int(int* __restrict__ p, int n) {
    int i = blockIdx.x * blockDim.x + threadIdx.x;
    if (i < n) p[i] = 0;
}

__global__ void count2_kernel(const int* __restrict__ eiO, const int* __restrict__ eiS,
                              int e, int n, int* __restrict__ counts2) {
    int q = blockIdx.x * blockDim.x + threadIdx.x;
    if (q >= 2 * e) return;
    int ty = q >= e;
    int i = ty ? q - e : q;
    const int* ei = ty ? eiS : eiO;
    atomicAdd(&counts2[ty * n + ei[e + i]], 1);
}

__global__ void block_sum_kernel(const int* __restrict__ counts, int n, int* __restrict__ psum) {
    __shared__ int ws[16];
    int tid = threadIdx.x, lane = tid & 63, wid = tid >> 6;
    int i = blockIdx.x * 1024 + tid;
    int v = (i < n) ? counts[i] : 0;
#pragma unroll
    for (int o = 1; o < 64; o <<= 1) v += __shfl_xor(v, o);
    if (lane == 0) ws[wid] = v;
    __syncthreads();
    if (tid < 16) {
        int s = ws[tid];
#pragma unroll
        for (int o = 1; o < 16; o <<= 1) s += __shfl_xor(s, o, 16);
        if (tid == 0) psum[blockIdx.x] = s;
    }
}

// single block, 128 threads, nb <= 128
__global__ void scan_psum_big(int* __restrict__ psum, int nb, int* __restrict__ total) {
    __shared__ int wsum[2];
    int tid = threadIdx.x, lane = tid & 63, wid = tid >> 6;
    int v = (tid < nb) ? psum[tid] : 0;
    int x = v;
#pragma unroll
    for (int o = 1; o < 64; o <<= 1) {
        int t = __shfl_up(x, o);
        if (lane >= o) x += t;
    }
    if (lane == 63) wsum[wid] = x;
    __syncthreads();
    int base = (wid == 1) ? wsum[0] : 0;
    if (tid < nb) psum[tid] = base + x - v;   // exclusive
    if (tid == 127) *total = wsum[0] + wsum[1];
}

__global__ void scan_block_kernel(const int* __restrict__ counts, const int* __restrict__ psum,
                                  int n, int* __restrict__ row_ptr, int* __restrict__ cursor) {
    __shared__ int ws[16];
    int tid = threadIdx.x, lane = tid & 63, wid = tid >> 6;
    int i = blockIdx.x * 1024 + tid;
    int v = (i < n) ? counts[i] : 0;
    int x = v;
#pragma unroll
    for (int o = 1; o < 64; o <<= 1) {
        int t = __shfl_up(x, o);
        if (lane >= o) x += t;
    }
    if (lane == 63) ws[wid] = x;
    __syncthreads();
    if (tid < 16) {
        int s = ws[tid];
#pragma unroll
        for (int o = 1; o < 16; o <<= 1) {
            int t = __shfl_up(s, o, 16);
            if (tid >= o) s += t;
        }
        ws[tid] = s;
    }
    __syncthreads();
    int base = psum[blockIdx.x] + (wid ? ws[wid - 1] : 0);
    int excl = base + x - v;
    if (i < n) { row_ptr[i] = excl; cursor[i] = excl; }
}

__global__ void scatter2_kernel(const int* __restrict__ eiO, const int* __restrict__ eiS,
                                int e, int n, int* __restrict__ cursor2,
                                long long* __restrict__ cp2) {
    int q = blockIdx.x * blockDim.x + threadIdx.x;
    if (q >= 2 * e) return;
    int ty = q >= e;
    int i = ty ? q - e : q;
    const int* ei = ty ? eiS : eiO;
    int d = ei[e + i];
    int p = atomicAdd(&cursor2[ty * n + d], 1);
    cp2[p] = ((long long)i << 32) | (unsigned)ei[i];
}

// canonicalize slot order per row -> deterministic CSR (2N rows)
__global__ void sort_rows_kernel(const int* __restrict__ rp, long long* __restrict__ cp, int n) {
    int i = blockIdx.x * blockDim.x + threadIdx.x;
    if (i >= n) return;
    int r0 = rp[i], r1 = rp[i + 1];
    for (int a = r0 + 1; a < r1; a++) {
        long long v = cp[a];
        int b = a - 1;
        while (b >= r0 && cp[b] > v) {
            cp[b + 1] = cp[b];
            b--;
        }
        cp[b + 1] = v;
    }
}

// ============ pass A: per-edge raw attention weights, all (type, conv) in one launch ============
__global__ void alpha6_kernel(const int* __restrict__ eiO, const int* __restrict__ eiS,
                              const float* __restrict__ ssO, const float* __restrict__ sdO,
                              const float* __restrict__ ssS, const float* __restrict__ sdS,
                              float* __restrict__ alO, float* __restrict__ alS, int e, int n) {
    int q = blockIdx.x * blockDim.x + threadIdx.x;
    if (q >= 6 * e) return;
    int ty = q / (2 * e);
    int rem = q - ty * 2 * e;
    const size_t nb = (size_t)ty * n * 4;
    const size_t eb = (size_t)ty * e * 4;
    const int* ei;
    const float* ss;
    const float* sd;
    float* al;
    int i;
    if (rem < e) { ei = eiO; ss = ssO + nb; sd = sdO + nb; al = alO + eb; i = rem; }
    else         { ei = eiS; ss = ssS + nb; sd = sdS + nb; al = alS + eb; i = rem - e; }
    int s = ei[i], d = ei[e + i];
    float4 svs = *(const float4*)&ss[s * 4];
    float4 svd = *(const float4*)&ss[d * 4];
    float4 dvd = *(const float4*)&sd[d * 4];
    float4 a;
    a.x = __expf(lrelu(svs.x + dvd.x) - lrelu(svd.x + dvd.x));
    a.y = __expf(lrelu(svs.y + dvd.y) - lrelu(svd.y + dvd.y));
    a.z = __expf(lrelu(svs.z + dvd.z) - lrelu(svd.z + dvd.z));
    a.w = __expf(lrelu(svs.w + dvd.w) - lrelu(svd.w + dvd.w));
    *(float4*)&al[(size_t)i * 4] = a;
}

// ============ pass B batched: wave per (type, node); O/S joint loop, 2-edge unroll each ============
__global__ void gat_fused_b(const unsigned short* __restrict__ xpO, const float* __restrict__ alO,
                            const unsigned short* __restrict__ xpS, const float* __restrict__ alS,
                            const long long* __restrict__ cp2, const int* __restrict__ rp2,
                            const float* __restrict__ bgO, const float* __restrict__ bgS,
                            const float* __restrict__ embPart, const float* __restrict__ Wc,
                            const float* __restrict__ bc, float* __restrict__ out, int n) {
    const int wave = threadIdx.x >> 6, lane = threadIdx.x & 63;
    const int i3 = blockIdx.x * 4 + wave;
    if (i3 >= 3 * n) return;
    const int ty = i3 / n, i = i3 - ty * n;
    const int c = lane * 2, hh = lane >> 4;

    const unsigned short* xo = xpO + (size_t)ty * n * 128;
    const unsigned short* xs_ = xpS + (size_t)ty * n * 128;
    const float* alo = alO + (size_t)ty * NEDGES * 4;
    const float* als = alS + (size_t)ty * NEDGES * 4;

    const int r0o = rp2[i], r1o = rp2[i + 1];
    const int r0s = rp2[n + i], r1s = rp2[n + i + 1];

    float tO = 0.f, oxO = 0.f, oyO = 0.f;
    float tS = 0.f, oxS = 0.f, oyS = 0.f;
    int ko = r0o, ks = r0s;

    // 4 independent load chains per iteration (2 O-edges + 2 S-edges)
    while (ko + 2 <= r1o && ks + 2 <= r1s) {
        long long vo0 = cp2[ko], vo1 = cp2[ko + 1];
        long long vs0 = cp2[ks], vs1 = cp2[ks + 1];
        int so0 = (int)(vo0 & 0xFFFFFFFFll), eo0 = (int)(vo0 >> 32);
        int so1 = (int)(vo1 & 0xFFFFFFFFll), eo1 = (int)(vo1 >> 32);
        int sx0 = (int)(vs0 & 0xFFFFFFFFll), es0 = (int)(vs0 >> 32);
        int sx1 = (int)(vs1 & 0xFFFFFFFFll), es1 = (int)(vs1 >> 32);
        float ao0 = alo[(size_t)eo0 * 4 + hh], ao1 = alo[(size_t)eo1 * 4 + hh];
        float as0 = als[(size_t)es0 * 4 + hh], as1 = als[(size_t)es1 * 4 + hh];
        unsigned uo0 = *(const unsigned*)&xo[(size_t)so0 * 128 + c];
        unsigned uo1 = *(const unsigned*)&xo[(size_t)so1 * 128 + c];
        unsigned us0 = *(const unsigned*)&xs_[(size_t)sx0 * 128 + c];
        unsigned us1 = *(const unsigned*)&xs_[(size_t)sx1 * 128 + c];
        tO += ao0 + ao1;
        oxO += ao0 * __uint_as_float(uo0 << 16) + ao1 * __uint_as_float(uo1 << 16);
        oyO += ao0 * __uint_as_float(uo0 & 0xFFFF0000u) + ao1 * __uint_as_float(uo1 & 0xFFFF0000u);
        tS += as0 + as1;
        oxS += as0 * __uint_as_float(us0 << 16) + as1 * __uint_as_float(us1 << 16);
        oyS += as0 * __uint_as_float(us0 & 0xFFFF0000u) + as1 * __uint_as_float(us1 & 0xFFFF0000u);
        ko += 2; ks += 2;
    }
    while (ko < r1o && ks < r1s) {
        long long vo = cp2[ko], vs = cp2[ks];
        int so = (int)(vo & 0xFFFFFFFFll), eo = (int)(vo >> 32);
        int sx = (int)(vs & 0xFFFFFFFFll), es = (int)(vs >> 32);
        float ao = alo[(size_t)eo * 4 + hh];
        float as_ = als[(size_t)es * 4 + hh];
        unsigned uo = *(const unsigned*)&xo[(size_t)so * 128 + c];
        unsigned us = *(const unsigned*)&xs_[(size_t)sx * 128 + c];
        tO += ao;
        oxO += ao * __uint_as_float(uo << 16);
        oyO += ao * __uint_as_float(uo & 0xFFFF0000u);
        tS += as_;
        oxS += as_ * __uint_as_float(us << 16);
        oyS += as_ * __uint_as_float(us & 0xFFFF0000u);
        ko++; ks++;
    }
    for (; ko + 2 <= r1o; ko += 2) {
        long long vo0 = cp2[ko], vo1 = cp2[ko + 1];
        int so0 = (int)(vo0 & 0xFFFFFFFFll), eo0 = (int)(vo0 >> 32);
        int so1 = (int)(vo1 & 0xFFFFFFFFll), eo1 = (int)(vo1 >> 32);
        float ao0 = alo[(size_t)eo0 * 4 + hh], ao1 = alo[(size_t)eo1 * 4 + hh];
        unsigned uo0 = *(const unsigned*)&xo[(size_t)so0 * 128 + c];
        unsigned uo1 = *(const unsigned*)&xo[(size_t)so1 * 128 + c];
        tO += ao0 + ao1;
        oxO += ao0 * __uint_as_float(uo0 << 16) + ao1 * __uint_as_float(uo1 << 16);
        oyO += ao0 * __uint_as_float(uo0 & 0xFFFF0000u) + ao1 * __uint_as_float(uo1 & 0xFFFF0000u);
    }
    for (; ko < r1o; ko++) {
        long long vo = cp2[ko];
        int so = (int)(vo & 0xFFFFFFFFll), eo = (int)(vo >> 32);
        float ao = alo[(size_t)eo * 4 + hh];
        unsigned uo = *(const unsigned*)&xo[(size_t)so * 128 + c];
        tO += ao;
        oxO += ao * __uint_as_float(uo << 16);
        oyO += ao * __uint_as_float(uo & 0xFFFF0000u);
    }
    for (; ks + 2 <= r1s; ks += 2) {
        long long vs0 = cp2[ks], vs1 = cp2[ks + 1];
        int sx0 = (int)(vs0 & 0xFFFFFFFFll), es0 = (int)(vs0 >> 32);
        int sx1 = (int)(vs1 & 0xFFFFFFFFll), es1 = (int)(vs1 >> 32);
        float as0 = als[(size_t)es0 * 4 + hh], as1 = als[(size_t)es1 * 4 + hh];
        unsigned us0 = *(const unsigned*)&xs_[(size_t)sx0 * 128 + c];
        unsigned us1 = *(const unsigned*)&xs_[(size_t)sx1 * 128 + c];
        tS += as0 + as1;
        oxS += as0 * __uint_as_float(us0 << 16) + as1 * __uint_as_float(us1 << 16);
        oyS += as0 * __uint_as_float(us0 & 0xFFFF0000u) + as1 * __uint_as_float(us1 & 0xFFFF0000u);
    }
    for (; ks < r1s; ks++) {
        long long vs = cp2[ks];
        int sx = (int)(vs & 0xFFFFFFFFll), es = (int)(vs >> 32);
        float as_ = als[(size_t)es * 4 + hh];
        unsigned us = *(const unsigned*)&xs_[(size_t)sx * 128 + c];
        tS += as_;
        oxS += as_ * __uint_as_float(us << 16);
        oyS += as_ * __uint_as_float(us & 0xFFFF0000u);
    }
    {   // self-loops: raw alpha = exp(0) = 1
        unsigned uo = *(const unsigned*)&xo[(size_t)i * 128 + c];
        unsigned us = *(const unsigned*)&xs_[(size_t)i * 128 + c];
        oxO += __uint_as_float(uo << 16);
        oyO += __uint_as_float(uo & 0xFFFF0000u);
        oxS += __uint_as_float(us << 16);
        oyS += __uint_as_float(us & 0xFFFF0000u);
    }
    const float idO = 1.f / (tO + 1.f), idS = 1.f / (tS + 1.f);
    float fx = idO * oxO + idS * oxS + bgO[c] + bgS[c];
    float fy = idO * oyO + idS * oyS + bgO[c + 1] + bgS[c + 1];

    float2 w = *(const float2*)&Wc[c];
    float p = fx * w.x + fy * w.y;
#pragma unroll
    for (int o = 32; o > 0; o >>= 1) p += __shfl_xor(p, o);
    if (lane == 0) out[i3] = 1.f / (1.f + expf(-(p + embPart[i3] + bc[0])));
}

extern "C" void kernel_launch(void* const* d_in, const int* in_sizes, int n_in,
                              void* d_out, int out_size, void* d_ws, size_t ws_size,
                              hipStream_t stream) {
    const int N = NNODES, E = NEDGES;
    const float* x_acc = (const float*)d_in[0];
    const float* x_cus = (const float*)d_in[1];
    const float* x_txn = (const float*)d_in[2];
    const int* ei_owns = (const int*)d_in[4];
    const int* ei_shr = (const int*)d_in[5];
    const float* W_acc = (const float*)d_in[6];
    const float* b_acc = (const float*)d_in[7];
    const float* W_cus = (const float*)d_in[8];
    const float* b_cus = (const float*)d_in[9];
    const float* W_txn = (const float*)d_in[10];
    const float* b_txn = (const float*)d_in[11];
    const float* Wg_o = (const float*)d_in[12];
    const float* as_o = (const float*)d_in[13];
    const float* ad_o = (const float*)d_in[14];
    const float* bg_o = (const float*)d_in[15];
    const float* Wg_s = (const float*)d_in[16];
    const float* as_s = (const float*)d_in[17];
    const float* ad_s = (const float*)d_in[18];
    const float* bg_s = (const float*)d_in[19];
    const float* W_cls = (const float*)d_in[20];
    const float* b_cls = (const float*)d_in[21];
    float* out = (float*)d_out;

    float* wf = (float*)d_ws;
    int* iw = (int*)d_ws;
    // batched layout (all 3 types resident):
    unsigned short* xp_o3 = (unsigned short*)(wf + 0);          // 3N*128 bf16 = 9.6M f
    unsigned short* xp_s3 = (unsigned short*)(wf + 9600000);    // 9.6M f
    float* ss_o3 = wf + 19200000;                               // 3N*4 = 600k
    float* sd_o3 = wf + 19800000;
    float* ss_s3 = wf + 20400000;
    float* sd_s3 = wf + 21000000;
    float* al_o3 = wf + 21600000;                               // 3E*4 = 6M
    float* al_s3 = wf + 27600000;                               // 6M
    float* embPart = wf + 33600000;                             // 3N = 150k
    int* rp2    = iw + 33750008;                                // 2N+1
    long long* cp2 = (long long*)(iw + 33850016);               // 2E u64 (even int ofs)
    // CSR scratch overlaps al region (dead until alpha6 runs, after CSR completes):
    int* counts2 = (int*)al_o3;                                 // 2N
    int* cursor2 = counts2 + 100000;                            // 2N
    int* psum    = cursor2 + 100000;                            // 128

    const int gN2 = (2 * N + 255) / 256;
    const int gE2 = (2 * E + 255) / 256;
    const int gS2 = (2 * N + 1023) / 1024;  // 98 blocks
    const int gXP = 3 * NTILES;
    const int gA = (3 * N + 3) / 4;
    const int gA6 = (6 * E + 255) / 256;

    // batched CSR for both edge types (src = row 0, dst = row 1); canonical slot order via sort
    zero_int<<<gN2, 256, 0, stream>>>(counts2, 2 * N);
    count2_kernel<<<gE2, 256, 0, stream>>>(ei_owns, ei_shr, E, N, counts2);
    block_sum_kernel<<<gS2, 1024, 0, stream>>>(counts2, 2 * N, psum);
    scan_psum_big<<<1, 128, 0, stream>>>(psum, gS2, rp2 + 2 * N);
    scan_block_kernel<<<gS2, 1024, 0, stream>>>(counts2, psum, 2 * N, rp2, cursor2);
    scatter2_kernel<<<gE2, 256, 0, stream>>>(ei_owns, ei_shr, E, N, cursor2, cp2);
    sort_rows_kernel<<<gN2, 256, 0, stream>>>(rp2, cp2, 2 * N);

    // batched: all 3 types in one xp launch -> one alpha launch -> one aggregate launch
    xp_all_b<<<gXP, 256, 0, stream>>>(x_acc, x_cus, x_txn,
                                      W_acc, b_acc, W_cus, b_cus, W_txn, b_txn,
                                      Wg_o, as_o, ad_o, Wg_s, as_s, ad_s, W_cls,
                                      embPart, xp_o3, xp_s3,
                                      ss_o3, sd_o3, ss_s3, sd_s3, N);
    alpha6_kernel<<<gA6, 256, 0, stream>>>(ei_owns, ei_shr,
                                           ss_o3, sd_o3, ss_s3, sd_s3,
                                           al_o3, al_s3, E, N);
    gat_fused_b<<<gA, 256, 0, stream>>>(xp_o3, al_o3, xp_s3, al_s3,
                                        cp2, rp2, bg_o, bg_s,
                                        embPart, W_cls, b_cls, out, N);
}